// Round 3
// baseline (2405.716 us; speedup 1.0000x reference)
//
#include <hip/hip_runtime.h>

#define DEV __device__ __forceinline__

namespace {

typedef __attribute__((ext_vector_type(8))) short short8;
typedef __attribute__((ext_vector_type(4))) float f32x4;

constexpr int B_ = 16, N_ = 4096, S_ = 512, CF_ = 64;
constexpr float EPS_ = 1e-5f;

// ---- ws layout (float units) ----
constexpr int IDX0_OFF  = 0;                    // B*S*32 ints
constexpr int IDX1_OFF  = 262144;               // B*S*64 ints
constexpr int STATS_OFF = IDX1_OFF + 524288;    // 6*256 f
constexpr int AC_OFF    = STATS_OFF + 1536;     // 6*256 f
constexpr int WP_OFF    = AC_OFF + 1536;        // 43008 ushorts = 21504 f
constexpr int MAXT_OFF  = WP_OFF + 21504;       // 8192*128 f
constexpr int FEATT_OFF = MAXT_OFF + 1048576;   // 4194304 ushorts = 2097152 f
constexpr int Y0_OFF    = FEATT_OFF + 2097152;  // up to 33.55M ushorts = 16777216 f
constexpr int Y1_OFF    = Y0_OFF + 16777216;    // up to 50.33M ushorts = 25165824 f
constexpr size_t WS_NEED_FT   = (size_t)Y0_OFF * 4;
constexpr size_t WS_NEED_PIPE = (size_t)(Y1_OFF + 25165824) * 4;

// packed-weight sub-offsets (ushort units)
constexpr int WP00 = 0,     WP01 = 6144,  WP02 = 10240;
constexpr int WP10 = 18432, WP11 = 24576, WP12 = 30720;

DEV int rfl(int x) { return __builtin_amdgcn_readfirstlane(x); }

DEV unsigned short f2bf(float x) {  // RNE float->bf16
  unsigned u = __float_as_uint(x);
  u += 0x7fff + ((u >> 16) & 1);
  return (unsigned short)(u >> 16);
}
DEV float bf2f(unsigned short u) { return __uint_as_float((unsigned)u << 16); }

// ===================== FPS (1 barrier / iter) =====================
__global__ __launch_bounds__(1024) void fps_kernel(const float* __restrict__ xyz,
                                                   float* __restrict__ newxyz) {
  __shared__ float px[N_], py[N_], pz[N_];
  __shared__ float swv[2][16];
  __shared__ int   swi[2][16];
  const int b = blockIdx.x, t = threadIdx.x;
  const int lane = t & 63, wv = t >> 6;
  const float* xb = xyz + (size_t)b * N_ * 3;
  for (int i = t; i < N_; i += 1024) {
    px[i] = xb[i * 3 + 0];
    py[i] = xb[i * 3 + 1];
    pz[i] = xb[i * 3 + 2];
  }
  __syncthreads();
  float dr[4] = {1e10f, 1e10f, 1e10f, 1e10f};
  int last = 0;
  if (t == 0) {
    newxyz[(size_t)(b * S_ + 0) * 3 + 0] = px[0];
    newxyz[(size_t)(b * S_ + 0) * 3 + 1] = py[0];
    newxyz[(size_t)(b * S_ + 0) * 3 + 2] = pz[0];
  }
  for (int it = 1; it < S_; ++it) {
    const int p = it & 1;
    const float cx = px[last], cy = py[last], cz = pz[last];
    float bv = -1.0f;
    int bi = 0x7fffffff;
#pragma unroll
    for (int j = 0; j < 4; ++j) {
      const int i = t + j * 1024;
      float d;
      {
#pragma clang fp contract(off)
        float dx = px[i] - cx, dy = py[i] - cy, dz = pz[i] - cz;
        d = (dx * dx + dy * dy) + dz * dz;
      }
      float dm = dr[j] < d ? dr[j] : d;
      dr[j] = dm;
      if (dm > bv) { bv = dm; bi = i; }  // i ascending -> strict > keeps lowest index
    }
#pragma unroll
    for (int m = 1; m < 64; m <<= 1) {
      float ov = __shfl_xor(bv, m);
      int   oi = __shfl_xor(bi, m);
      if (ov > bv || (ov == bv && oi < bi)) { bv = ov; bi = oi; }
    }
    if (lane == 0) { swv[p][wv] = bv; swi[p][wv] = bi; }
    __syncthreads();
    // all threads redundantly reduce the 16 slots (broadcast reads, no 2nd barrier)
    float rv = swv[p][0];
    int   ri = swi[p][0];
#pragma unroll
    for (int r = 1; r < 16; ++r) {
      const float v = swv[p][r];
      const int   i = swi[p][r];
      if (v > rv || (v == rv && i < ri)) { rv = v; ri = i; }
    }
    last = ri;
    if (t == 0) {
      newxyz[(size_t)(b * S_ + it) * 3 + 0] = px[ri];
      newxyz[(size_t)(b * S_ + it) * 3 + 1] = py[ri];
      newxyz[(size_t)(b * S_ + it) * 3 + 2] = pz[ri];
    }
  }
}

// ===================== Ball query =====================
template <int NS>
__global__ __launch_bounds__(256) void ballq_kernel(const float* __restrict__ xyz,
                                                    const float* __restrict__ newxyz,
                                                    int* __restrict__ idx, float r2) {
  __shared__ int sbuf[4][NS];
  const int wiv = threadIdx.x >> 6;
  const int lane = threadIdx.x & 63;
  const int cs = blockIdx.x * 4 + wiv;
  const int b = cs >> 9;
  const float cx = newxyz[(size_t)cs * 3 + 0];
  const float cy = newxyz[(size_t)cs * 3 + 1];
  const float cz = newxyz[(size_t)cs * 3 + 2];
  const float* xb = xyz + (size_t)b * N_ * 3;
  int* my = sbuf[wiv];
  int cnt = 0;
  for (int base = 0; base < N_; base += 64) {
    if (cnt >= NS) break;
    const int i = base + lane;
    float d;
    {
#pragma clang fp contract(off)
      float dx = xb[i * 3 + 0] - cx, dy = xb[i * 3 + 1] - cy, dz = xb[i * 3 + 2] - cz;
      d = (dx * dx + dy * dy) + dz * dz;
    }
    const bool q = d < r2;
    const unsigned long long m = __ballot(q);
    if (q) {
      int pos = cnt + __popcll(m & ((1ull << lane) - 1ull));
      if (pos < NS) my[pos] = i;
    }
    cnt += __popcll(m);
  }
  __syncthreads();
  const int c = cnt < NS ? cnt : NS;
  const int first = my[0];
  for (int j = lane; j < NS; j += 64) idx[(size_t)cs * NS + j] = (j < c) ? my[j] : first;
}

// ===================== feat transpose to (B,N,64) bf16 =====================
__global__ __launch_bounds__(256) void featT_kernel(const float* __restrict__ feat,
                                                    unsigned short* __restrict__ featT) {
  __shared__ unsigned short tile[64][65];
  const int t = threadIdx.x;
  const int b = blockIdx.x >> 6, nc = blockIdx.x & 63;
  const int n0 = nc * 64;
  for (int i = t; i < 64 * 64; i += 256) {
    int c = i >> 6, n = i & 63;
    tile[c][n] = f2bf(feat[((size_t)b * CF_ + c) * N_ + n0 + n]);
  }
  __syncthreads();
  for (int i = t; i < 64 * 64; i += 256) {
    int n = i >> 6, c = i & 63;
    featT[((size_t)b * N_ + n0 + n) * 64 + c] = tile[c][n];
  }
}

// ===================== weight pack into B-fragment order =====================
__global__ __launch_bounds__(256) void pack_w_kernel(
    const float* __restrict__ w00, const float* __restrict__ w01, const float* __restrict__ w02,
    const float* __restrict__ w10, const float* __restrict__ w11, const float* __restrict__ w12,
    unsigned short* __restrict__ wp) {
  const int id = blockIdx.x * 256 + threadIdx.x;
  const float* w; int off, KK, CINW, base; bool perm;
  if (id < 768)       { w = w00; off = WP00; KK = 3; CINW = 67; perm = true;  base = 0; }
  else if (id < 1280) { w = w01; off = WP01; KK = 2; CINW = 64; perm = false; base = 768; }
  else if (id < 2304) { w = w02; off = WP02; KK = 2; CINW = 64; perm = false; base = 1280; }
  else if (id < 3072) { w = w10; off = WP10; KK = 3; CINW = 67; perm = true;  base = 2304; }
  else if (id < 3840) { w = w11; off = WP11; KK = 2; CINW = 64; perm = false; base = 3072; }
  else if (id < 5376) { w = w12; off = WP12; KK = 3; CINW = 96; perm = false; base = 3840; }
  else return;
  const int lid = id - base;
  const int lane = lid & 63, fr = lid >> 6;
  const int kk = fr % KK, nt = fr / KK;
  const int ccol = nt * 16 + (lane & 15);
  const int kbase = kk * 32 + (lane >> 4) * 8;
  unsigned short* dst = wp + off + (size_t)lid * 8;
#pragma unroll
  for (int j = 0; j < 8; ++j) {
    const int k = kbase + j;
    int cin;
    if (perm) cin = (k < 64) ? k + 3 : (k < 67 ? k - 64 : -1);
    else      cin = (k < CINW) ? k : -1;
    float f = (cin >= 0) ? w[ccol * CINW + cin] : 0.f;
    dst[j] = f2bf(f);
  }
}

// ===================== stats flush helper =====================
template <int DS>
DEV void flush_stats(const float* ssum, const float* ssq, int lane, float* __restrict__ sg) {
  constexpr int NTS = DS / 16;
#pragma unroll
  for (int nt = 0; nt < NTS; ++nt) {
    float s = ssum[nt], q = ssq[nt];
    s += __shfl_xor(s, 16); q += __shfl_xor(q, 16);
    s += __shfl_xor(s, 32); q += __shfl_xor(q, 32);
    if (lane < 16) {
      atomicAdd(&sg[nt * 16 + lane], s);
      atomicAdd(&sg[DS + nt * 16 + lane], q);
    }
  }
}

// ===================== pipeline P1: gather + layer0 (no LDS, no barriers) =====================
template <int K>
__global__ __launch_bounds__(256) void p1_kernel(
    const float* __restrict__ xyz, const unsigned short* __restrict__ featT,
    const float* __restrict__ newxyz, const int* __restrict__ idx,
    const unsigned short* __restrict__ wp0, const float* __restrict__ b0,
    unsigned short* __restrict__ y0, float* __restrict__ stats_out) {
  const int t = threadIdx.x, lane = t & 63;
  const int wid = rfl(t >> 6);
  const int col = lane & 15, khi = lane >> 4;
  constexpr int MT = (B_ * S_ * K) / 16;
  const int w0 = blockIdx.x * 4 + wid;
  short8 bfr[12];
#pragma unroll
  for (int i = 0; i < 12; ++i)
    bfr[i] = *reinterpret_cast<const short8*>(wp0 + ((size_t)i * 64 + lane) * 8);
  float bb[4];
#pragma unroll
  for (int nt = 0; nt < 4; ++nt) bb[nt] = b0[nt * 16 + col];
  float ssum[4] = {0.f, 0.f, 0.f, 0.f}, ssq[4] = {0.f, 0.f, 0.f, 0.f};
  for (int mt = w0; mt < MT; mt += 8192) {
    const int row = mt * 16 + col;
    const int cs = row / K;
    const int b = cs >> 9;
    const int pi = idx[row];
    const unsigned short* fr = featT + (((size_t)b * N_ + pi) << 6);
    const short8 a0 = *reinterpret_cast<const short8*>(fr + khi * 8);
    const short8 a1 = *reinterpret_cast<const short8*>(fr + 32 + khi * 8);
    short8 a2 = {0, 0, 0, 0, 0, 0, 0, 0};
    if (khi == 0) {
      const float* P = xyz + ((size_t)b * N_ + pi) * 3;
      const float* C = newxyz + (size_t)cs * 3;
      a2[0] = (short)f2bf(P[0] - C[0]);
      a2[1] = (short)f2bf(P[1] - C[1]);
      a2[2] = (short)f2bf(P[2] - C[2]);
    }
#pragma unroll
    for (int nt = 0; nt < 4; ++nt) {
      f32x4 a = {0.f, 0.f, 0.f, 0.f};
      a = __builtin_amdgcn_mfma_f32_16x16x32_bf16(a0, bfr[nt * 3 + 0], a, 0, 0, 0);
      a = __builtin_amdgcn_mfma_f32_16x16x32_bf16(a1, bfr[nt * 3 + 1], a, 0, 0, 0);
      a = __builtin_amdgcn_mfma_f32_16x16x32_bf16(a2, bfr[nt * 3 + 2], a, 0, 0, 0);
#pragma unroll
      for (int j = 0; j < 4; ++j) {
        const float y = a[j] + bb[nt];
        ssum[nt] += y; ssq[nt] += y * y;
        y0[(size_t)(mt * 16 + khi * 4 + j) * 64 + nt * 16 + col] = f2bf(y);
      }
    }
  }
  flush_stats<64>(ssum, ssq, lane, stats_out);
}

// ===================== pipeline P2: norm(y_in) -> layer -> y_out =====================
template <int DIN, int DOUT>
__global__ __launch_bounds__(256) void p2_kernel(
    const unsigned short* __restrict__ yin, const unsigned short* __restrict__ wp,
    const float* __restrict__ bias, const float* __restrict__ ac,
    unsigned short* __restrict__ yout, float* __restrict__ stats_out, int MT) {
  constexpr int KK = DIN / 32, NT = DOUT / 16;
  const int t = threadIdx.x, lane = t & 63;
  const int wid = rfl(t >> 6);
  const int col = lane & 15, khi = lane >> 4;
  const int w0 = blockIdx.x * 4 + wid;
  short8 bfr[NT * KK];
#pragma unroll
  for (int i = 0; i < NT * KK; ++i)
    bfr[i] = *reinterpret_cast<const short8*>(wp + ((size_t)i * 64 + lane) * 8);
  float bb[NT];
#pragma unroll
  for (int nt = 0; nt < NT; ++nt) bb[nt] = bias[nt * 16 + col];
  float ar[KK][8], cr[KK][8];
#pragma unroll
  for (int kk = 0; kk < KK; ++kk)
#pragma unroll
    for (int j = 0; j < 8; ++j) {
      const int ch = kk * 32 + khi * 8 + j;
      ar[kk][j] = ac[ch];
      cr[kk][j] = ac[DIN + ch];
    }
  float ssum[NT], ssq[NT];
#pragma unroll
  for (int nt = 0; nt < NT; ++nt) { ssum[nt] = 0.f; ssq[nt] = 0.f; }
  for (int mt = w0; mt < MT; mt += 8192) {
    const size_t rb = (size_t)(mt * 16 + col) * DIN;
    short8 af[KK];
#pragma unroll
    for (int kk = 0; kk < KK; ++kk) {
      const short8 raw = *reinterpret_cast<const short8*>(yin + rb + kk * 32 + khi * 8);
#pragma unroll
      for (int j = 0; j < 8; ++j) {
        const float v = bf2f((unsigned short)raw[j]) * ar[kk][j] + cr[kk][j];
        af[kk][j] = (short)f2bf(fmaxf(v, 0.f));
      }
    }
#pragma unroll
    for (int nt = 0; nt < NT; ++nt) {
      f32x4 a = {0.f, 0.f, 0.f, 0.f};
#pragma unroll
      for (int kk = 0; kk < KK; ++kk)
        a = __builtin_amdgcn_mfma_f32_16x16x32_bf16(af[kk], bfr[nt * KK + kk], a, 0, 0, 0);
#pragma unroll
      for (int j = 0; j < 4; ++j) {
        const float y = a[j] + bb[nt];
        ssum[nt] += y; ssq[nt] += y * y;
        yout[(size_t)(mt * 16 + khi * 4 + j) * DOUT + nt * 16 + col] = f2bf(y);
      }
    }
  }
  flush_stats<DOUT>(ssum, ssq, lane, stats_out);
}

// ===================== pipeline P3: norm(y1) -> layer2 -> stats + k-max =====================
template <int DIN, int K>
__global__ __launch_bounds__(256) void p3_kernel(
    const unsigned short* __restrict__ yin, const unsigned short* __restrict__ wp,
    const float* __restrict__ bias, const float* __restrict__ ac,
    float* __restrict__ maxtmp, float* __restrict__ stats_out) {
  constexpr int KK = DIN / 32, NT = 8;
  const int t = threadIdx.x, lane = t & 63;
  const int wid = rfl(t >> 6);
  const int col = lane & 15, khi = lane >> 4;
  const int c = blockIdx.x * 4 + wid;  // 8192 waves == 8192 centers
  short8 bfr[NT * KK];
#pragma unroll
  for (int i = 0; i < NT * KK; ++i)
    bfr[i] = *reinterpret_cast<const short8*>(wp + ((size_t)i * 64 + lane) * 8);
  float bb[NT];
#pragma unroll
  for (int nt = 0; nt < NT; ++nt) bb[nt] = bias[nt * 16 + col];
  float ar[KK][8], cr[KK][8];
#pragma unroll
  for (int kk = 0; kk < KK; ++kk)
#pragma unroll
    for (int j = 0; j < 8; ++j) {
      const int ch = kk * 32 + khi * 8 + j;
      ar[kk][j] = ac[ch];
      cr[kk][j] = ac[DIN + ch];
    }
  float ssum[NT], ssq[NT], mx[NT];
#pragma unroll
  for (int nt = 0; nt < NT; ++nt) { ssum[nt] = 0.f; ssq[nt] = 0.f; mx[nt] = -3.4e38f; }
#pragma unroll
  for (int m = 0; m < K / 16; ++m) {
    const size_t rb = (size_t)(c * K + m * 16 + col) * DIN;
    short8 af[KK];
#pragma unroll
    for (int kk = 0; kk < KK; ++kk) {
      const short8 raw = *reinterpret_cast<const short8*>(yin + rb + kk * 32 + khi * 8);
#pragma unroll
      for (int j = 0; j < 8; ++j) {
        const float v = bf2f((unsigned short)raw[j]) * ar[kk][j] + cr[kk][j];
        af[kk][j] = (short)f2bf(fmaxf(v, 0.f));
      }
    }
#pragma unroll
    for (int nt = 0; nt < NT; ++nt) {
      f32x4 a = {0.f, 0.f, 0.f, 0.f};
#pragma unroll
      for (int kk = 0; kk < KK; ++kk)
        a = __builtin_amdgcn_mfma_f32_16x16x32_bf16(af[kk], bfr[nt * KK + kk], a, 0, 0, 0);
#pragma unroll
      for (int j = 0; j < 4; ++j) {
        const float y = a[j] + bb[nt];
        ssum[nt] += y; ssq[nt] += y * y;
        mx[nt] = fmaxf(mx[nt], y);
      }
    }
  }
#pragma unroll
  for (int nt = 0; nt < NT; ++nt) {
    mx[nt] = fmaxf(mx[nt], __shfl_xor(mx[nt], 16));
    mx[nt] = fmaxf(mx[nt], __shfl_xor(mx[nt], 32));
  }
  if (lane < 16) {
#pragma unroll
    for (int nt = 0; nt < NT; ++nt) maxtmp[(size_t)c * 128 + nt * 16 + lane] = mx[nt];
  }
  flush_stats<128>(ssum, ssq, lane, stats_out);
}

// ===================== fallback path (round-2 stage_mfma) =====================
template <int K, bool FT>
DEV void gather_tile(unsigned short* sX, const float* __restrict__ xyz,
                     const float* __restrict__ feat, const unsigned short* __restrict__ featT,
                     const float* __restrict__ newxyz, const int* __restrict__ idx, int tile) {
  const int t = threadIdx.x, r = t & 63, c4 = t >> 6;
  const int rep = r / K, k = r % K;
  const int cs = tile * (64 / K) + rep, b = cs >> 9;
  const int pi = idx[(size_t)cs * K + k];
  unsigned short* dst = sX + r * 104;
  if (FT) {
    const unsigned short* src = featT + (((size_t)b * N_ + pi) << 6) + c4 * 16;
    *reinterpret_cast<short8*>(dst + c4 * 16)     = *reinterpret_cast<const short8*>(src);
    *reinterpret_cast<short8*>(dst + c4 * 16 + 8) = *reinterpret_cast<const short8*>(src + 8);
  } else {
#pragma unroll
    for (int j = 0; j < 16; ++j) {
      const int ch = c4 * 16 + j;
      dst[ch] = f2bf(feat[((size_t)b * CF_ + ch) * N_ + pi]);
    }
  }
  if (c4 == 0) {
    const float* P = xyz + ((size_t)b * N_ + pi) * 3;
    const float* C = newxyz + (size_t)cs * 3;
    dst[64] = f2bf(P[0] - C[0]);
    dst[65] = f2bf(P[1] - C[1]);
    dst[66] = f2bf(P[2] - C[2]);
  }
}

template <int NTILES, int KK>
DEV void layer_mfma(const unsigned short* sIn, int stride, const unsigned short* __restrict__ wp,
                    int lane, int wid, f32x4* acc) {
  short8 af[KK];
  const int arow = wid * 16 + (lane & 15);
  const int kof = (lane >> 4) * 8;
#pragma unroll
  for (int kk = 0; kk < KK; ++kk)
    af[kk] = *reinterpret_cast<const short8*>(sIn + arow * stride + kk * 32 + kof);
#pragma unroll
  for (int nt = 0; nt < NTILES; ++nt) {
    f32x4 a = {0.f, 0.f, 0.f, 0.f};
#pragma unroll
    for (int kk = 0; kk < KK; ++kk) {
      short8 bf = *reinterpret_cast<const short8*>(wp + ((size_t)(nt * KK + kk) * 64 + lane) * 8);
      a = __builtin_amdgcn_mfma_f32_16x16x32_bf16(af[kk], bf, a, 0, 0, 0);
    }
    acc[nt] = a;
  }
}

template <int K, int D0, int D1, int D2, int STAGE, bool FT>
__global__ __launch_bounds__(256) void stage_mfma(
    const float* __restrict__ xyz, const float* __restrict__ feat,
    const unsigned short* __restrict__ featT, const float* __restrict__ newxyz,
    const int* __restrict__ idx,
    const unsigned short* __restrict__ wp0, const unsigned short* __restrict__ wp1,
    const unsigned short* __restrict__ wp2,
    const float* __restrict__ b0, const float* __restrict__ b1, const float* __restrict__ b2,
    const float* __restrict__ ac0, const float* __restrict__ ac1,
    float* __restrict__ stats_out, float* __restrict__ maxtmp) {
  constexpr int CPB = 64 / K, NT = (B_ * S_) / CPB;
  constexpr int ST0 = 104, ST1 = 72, ST2 = (D1 == 96) ? 104 : 72;
  constexpr int KK0 = 3, KK1 = D0 / 32, KK2 = D1 / 32;
  constexpr int NT0 = D0 / 16, NT1 = D1 / 16, NT2 = D2 / 16;
  constexpr int DS = (STAGE == 1) ? D0 : (STAGE == 2) ? D1 : D2;
  constexpr int NTS = DS / 16;

  __shared__ unsigned short sX[64 * ST0];
  __shared__ unsigned short sY0[(STAGE >= 2) ? 64 * ST1 : 8];
  __shared__ unsigned short sY1[(STAGE == 3) ? 64 * ST2 : 8];
  __shared__ float smax[(STAGE == 3) ? 512 : 4];

  const int t = threadIdx.x, lane = t & 63;
  const int wid = rfl(t >> 6);
  const int col = lane & 15, khi = lane >> 4;

  for (int i = t; i < 64 * 37; i += 256) sX[(i / 37) * ST0 + 67 + (i % 37)] = 0;

  float b0r[NT0], a0r[NT0], c0r[NT0];
  float b1r[NT1], a1r[NT1], c1r[NT1];
  float b2r[NT2];
#pragma unroll
  for (int nt = 0; nt < NT0; ++nt) {
    b0r[nt] = b0[nt * 16 + col];
    if constexpr (STAGE >= 2) {
      a0r[nt] = ac0[nt * 16 + col];
      c0r[nt] = ac0[D0 + nt * 16 + col];
    }
  }
  if constexpr (STAGE >= 2) {
#pragma unroll
    for (int nt = 0; nt < NT1; ++nt) {
      b1r[nt] = b1[nt * 16 + col];
      if constexpr (STAGE == 3) {
        a1r[nt] = ac1[nt * 16 + col];
        c1r[nt] = ac1[D1 + nt * 16 + col];
      }
    }
  }
  if constexpr (STAGE == 3) {
#pragma unroll
    for (int nt = 0; nt < NT2; ++nt) b2r[nt] = b2[nt * 16 + col];
  }

  float ssum[NTS], ssq[NTS];
#pragma unroll
  for (int nt = 0; nt < NTS; ++nt) { ssum[nt] = 0.f; ssq[nt] = 0.f; }

  for (int tile = blockIdx.x; tile < NT; tile += gridDim.x) {
    __syncthreads();
    gather_tile<K, FT>(sX, xyz, feat, featT, newxyz, idx, tile);
    __syncthreads();

    f32x4 acc0[NT0];
    layer_mfma<NT0, KK0>(sX, ST0, wp0, lane, wid, acc0);
    if constexpr (STAGE == 1) {
#pragma unroll
      for (int nt = 0; nt < NT0; ++nt) {
        const float bb = b0r[nt];
#pragma unroll
        for (int j = 0; j < 4; ++j) {
          const float y = acc0[nt][j] + bb;
          ssum[nt] += y; ssq[nt] += y * y;
        }
      }
    } else {
#pragma unroll
      for (int nt = 0; nt < NT0; ++nt) {
#pragma unroll
        for (int j = 0; j < 4; ++j) {
          float y = (acc0[nt][j] + b0r[nt]) * a0r[nt] + c0r[nt];
          y = fmaxf(y, 0.f);
          sY0[(wid * 16 + khi * 4 + j) * ST1 + nt * 16 + col] = f2bf(y);
        }
      }
      __syncthreads();
      f32x4 acc1[NT1];
      layer_mfma<NT1, KK1>(sY0, ST1, wp1, lane, wid, acc1);
      if constexpr (STAGE == 2) {
#pragma unroll
        for (int nt = 0; nt < NT1; ++nt) {
          const float bb = b1r[nt];
#pragma unroll
          for (int j = 0; j < 4; ++j) {
            const float y = acc1[nt][j] + bb;
            ssum[nt] += y; ssq[nt] += y * y;
          }
        }
      } else {
#pragma unroll
        for (int nt = 0; nt < NT1; ++nt) {
#pragma unroll
          for (int j = 0; j < 4; ++j) {
            float y = (acc1[nt][j] + b1r[nt]) * a1r[nt] + c1r[nt];
            y = fmaxf(y, 0.f);
            sY1[(wid * 16 + khi * 4 + j) * ST2 + nt * 16 + col] = f2bf(y);
          }
        }
        __syncthreads();
        f32x4 acc2[NT2];
        layer_mfma<NT2, KK2>(sY1, ST2, wp2, lane, wid, acc2);
#pragma unroll
        for (int nt = 0; nt < NT2; ++nt) {
          const float bb = b2r[nt];
          const float y0 = acc2[nt][0] + bb, y1 = acc2[nt][1] + bb;
          const float y2 = acc2[nt][2] + bb, y3 = acc2[nt][3] + bb;
          ssum[nt] += (y0 + y1) + (y2 + y3);
          ssq[nt] += (y0 * y0 + y1 * y1) + (y2 * y2 + y3 * y3);
          float m = fmaxf(fmaxf(y0, y1), fmaxf(y2, y3));
          m = fmaxf(m, __shfl_xor(m, 16));
          m = fmaxf(m, __shfl_xor(m, 32));
          if (lane < 16) smax[wid * 128 + nt * 16 + lane] = m;
        }
        __syncthreads();
        if constexpr (K == 64) {
          if (t < 128) {
            const float m = fmaxf(fmaxf(smax[t], smax[128 + t]), fmaxf(smax[256 + t], smax[384 + t]));
            maxtmp[(size_t)tile * 128 + t] = m;
          }
        } else {
          const int ce = t >> 7, ch = t & 127;
          const float m = fmaxf(smax[ce * 256 + ch], smax[ce * 256 + 128 + ch]);
          maxtmp[((size_t)(tile * 2 + ce)) * 128 + ch] = m;
        }
      }
    }
  }
  flush_stats<DS>(ssum, ssq, lane, stats_out);
}

__global__ void finalize_kernel(const float* __restrict__ stats, const float* __restrict__ g,
                                const float* __restrict__ beta, float* __restrict__ ac,
                                float n, int cout) {
  const int t = threadIdx.x;
  if (t < cout) {
    const float mu = stats[t] / n;
    const float var = stats[cout + t] / n - mu * mu;
    const float a = g[t] / sqrtf(var + EPS_);
    ac[t] = a;
    ac[cout + t] = beta[t] - mu * a;
  }
}

__global__ __launch_bounds__(256) void out_kernel(const float* __restrict__ maxtmp,
                                                  const float* __restrict__ ac2,
                                                  float* __restrict__ outf, int coff) {
  const int i = blockIdx.x * 256 + threadIdx.x;
  if (i >= B_ * 128 * S_) return;
  const int s = i & 511;
  const int o = (i >> 9) & 127;
  const int b = i >> 16;
  const float a = ac2[o], c = ac2[128 + o];
  const float v = maxtmp[((size_t)(b * S_ + s)) * 128 + o];
  outf[((size_t)b * 256 + coff + o) * S_ + s] = a * v + c;
}

}  // namespace

extern "C" void kernel_launch(void* const* d_in, const int* in_sizes, int n_in,
                              void* d_out, int out_size, void* d_ws, size_t ws_size,
                              hipStream_t stream) {
  const float* xyz  = (const float*)d_in[0];
  const float* feat = (const float*)d_in[1];
  const float* w00 = (const float*)d_in[2];  const float* b00 = (const float*)d_in[3];
  const float* g00 = (const float*)d_in[4];  const float* be00 = (const float*)d_in[5];
  const float* w01 = (const float*)d_in[6];  const float* b01 = (const float*)d_in[7];
  const float* g01 = (const float*)d_in[8];  const float* be01 = (const float*)d_in[9];
  const float* w02 = (const float*)d_in[10]; const float* b02 = (const float*)d_in[11];
  const float* g02 = (const float*)d_in[12]; const float* be02 = (const float*)d_in[13];
  const float* w10 = (const float*)d_in[14]; const float* b10 = (const float*)d_in[15];
  const float* g10 = (const float*)d_in[16]; const float* be10 = (const float*)d_in[17];
  const float* w11 = (const float*)d_in[18]; const float* b11 = (const float*)d_in[19];
  const float* g11 = (const float*)d_in[20]; const float* be11 = (const float*)d_in[21];
  const float* w12 = (const float*)d_in[22]; const float* b12 = (const float*)d_in[23];
  const float* g12 = (const float*)d_in[24]; const float* be12 = (const float*)d_in[25];

  float* ws = (float*)d_ws;
  int* idx0 = (int*)(ws + IDX0_OFF);
  int* idx1 = (int*)(ws + IDX1_OFF);
  float* stats = ws + STATS_OFF;
  float* ac = ws + AC_OFF;
  unsigned short* wp = (unsigned short*)(ws + WP_OFF);
  float* maxtmp = ws + MAXT_OFF;
  unsigned short* featT = (unsigned short*)(ws + FEATT_OFF);
  unsigned short* y0us = (unsigned short*)(ws + Y0_OFF);
  unsigned short* y1us = (unsigned short*)(ws + Y1_OFF);

  const bool usePipe = ws_size >= WS_NEED_PIPE;
  const bool useFT   = ws_size >= WS_NEED_FT;

  float* outF = (float*)d_out;          // new_xyz (B,S,3)
  float* outFeat = outF + B_ * S_ * 3;  // (B,256,S)

  hipMemsetAsync(stats, 0, 6 * 256 * sizeof(float), stream);
  pack_w_kernel<<<21, 256, 0, stream>>>(w00, w01, w02, w10, w11, w12, wp);
  if (useFT) featT_kernel<<<1024, 256, 0, stream>>>(feat, featT);
  fps_kernel<<<16, 1024, 0, stream>>>(xyz, outF);
  ballq_kernel<32><<<2048, 256, 0, stream>>>(xyz, outF, idx0, 0.2f * 0.2f);
  ballq_kernel<64><<<2048, 256, 0, stream>>>(xyz, outF, idx1, 0.4f * 0.4f);

  const float n0 = (float)(B_ * S_ * 32);
  const float n1 = (float)(B_ * S_ * 64);

  if (usePipe) {
    // ---- scale 0: K=32, 67->64->64->128, rows = 262144 ----
    p1_kernel<32><<<2048, 256, 0, stream>>>(xyz, featT, outF, idx0, wp + WP00, b00,
                                            y0us, stats + 0 * 256);
    finalize_kernel<<<1, 128, 0, stream>>>(stats + 0 * 256, g00, be00, ac + 0 * 256, n0, 64);
    p2_kernel<64, 64><<<2048, 256, 0, stream>>>(y0us, wp + WP01, b01, ac + 0 * 256,
                                                y1us, stats + 1 * 256, 16384);
    finalize_kernel<<<1, 128, 0, stream>>>(stats + 1 * 256, g01, be01, ac + 1 * 256, n0, 64);
    p3_kernel<64, 32><<<2048, 256, 0, stream>>>(y1us, wp + WP02, b02, ac + 1 * 256,
                                                maxtmp, stats + 2 * 256);
    finalize_kernel<<<1, 128, 0, stream>>>(stats + 2 * 256, g02, be02, ac + 2 * 256, n0, 128);
    out_kernel<<<4096, 256, 0, stream>>>(maxtmp, ac + 2 * 256, outFeat, 0);

    // ---- scale 1: K=64, 67->64->96->128, rows = 524288 ----
    p1_kernel<64><<<2048, 256, 0, stream>>>(xyz, featT, outF, idx1, wp + WP10, b10,
                                            y0us, stats + 3 * 256);
    finalize_kernel<<<1, 128, 0, stream>>>(stats + 3 * 256, g10, be10, ac + 3 * 256, n1, 64);
    p2_kernel<64, 96><<<2048, 256, 0, stream>>>(y0us, wp + WP11, b11, ac + 3 * 256,
                                                y1us, stats + 4 * 256, 32768);
    finalize_kernel<<<1, 128, 0, stream>>>(stats + 4 * 256, g11, be11, ac + 4 * 256, n1, 96);
    p3_kernel<96, 64><<<2048, 256, 0, stream>>>(y1us, wp + WP12, b12, ac + 4 * 256,
                                                maxtmp, stats + 5 * 256);
    finalize_kernel<<<1, 128, 0, stream>>>(stats + 5 * 256, g12, be12, ac + 5 * 256, n1, 128);
    out_kernel<<<4096, 256, 0, stream>>>(maxtmp, ac + 5 * 256, outFeat, 128);
    return;
  }

#define LAUNCH_SCALE0(STG)                                                              \
  do {                                                                                  \
    if (useFT)                                                                          \
      stage_mfma<32, 64, 64, 128, STG, true><<<2048, 256, 0, stream>>>(                 \
          xyz, feat, featT, outF, idx0, wp + WP00, wp + WP01, wp + WP02, b00, b01, b02, \
          ac + 0 * 256, ac + 1 * 256, stats + (STG - 1) * 256, maxtmp);                 \
    else                                                                                \
      stage_mfma<32, 64, 64, 128, STG, false><<<2048, 256, 0, stream>>>(                \
          xyz, feat, featT, outF, idx0, wp + WP00, wp + WP01, wp + WP02, b00, b01, b02, \
          ac + 0 * 256, ac + 1 * 256, stats + (STG - 1) * 256, maxtmp);                 \
  } while (0)
#define LAUNCH_SCALE1(STG)                                                              \
  do {                                                                                  \
    if (useFT)                                                                          \
      stage_mfma<64, 64, 96, 128, STG, true><<<2048, 256, 0, stream>>>(                 \
          xyz, feat, featT, outF, idx1, wp + WP10, wp + WP11, wp + WP12, b10, b11, b12, \
          ac + 3 * 256, ac + 4 * 256, stats + (2 + STG) * 256, maxtmp);                 \
    else                                                                                \
      stage_mfma<64, 64, 96, 128, STG, false><<<2048, 256, 0, stream>>>(                \
          xyz, feat, featT, outF, idx1, wp + WP10, wp + WP11, wp + WP12, b10, b11, b12, \
          ac + 3 * 256, ac + 4 * 256, stats + (2 + STG) * 256, maxtmp);                 \
  } while (0)

  LAUNCH_SCALE0(1);
  finalize_kernel<<<1, 128, 0, stream>>>(stats + 0 * 256, g00, be00, ac + 0 * 256, n0, 64);
  LAUNCH_SCALE0(2);
  finalize_kernel<<<1, 128, 0, stream>>>(stats + 1 * 256, g01, be01, ac + 1 * 256, n0, 64);
  LAUNCH_SCALE0(3);
  finalize_kernel<<<1, 128, 0, stream>>>(stats + 2 * 256, g02, be02, ac + 2 * 256, n0, 128);
  out_kernel<<<4096, 256, 0, stream>>>(maxtmp, ac + 2 * 256, outFeat, 0);

  LAUNCH_SCALE1(1);
  finalize_kernel<<<1, 128, 0, stream>>>(stats + 3 * 256, g10, be10, ac + 3 * 256, n1, 64);
  LAUNCH_SCALE1(2);
  finalize_kernel<<<1, 128, 0, stream>>>(stats + 4 * 256, g11, be11, ac + 4 * 256, n1, 96);
  LAUNCH_SCALE1(3);
  finalize_kernel<<<1, 128, 0, stream>>>(stats + 5 * 256, g12, be12, ac + 5 * 256, n1, 128);
  out_kernel<<<4096, 256, 0, stream>>>(maxtmp, ac + 5 * 256, outFeat, 128);

#undef LAUNCH_SCALE0
#undef LAUNCH_SCALE1
}

// Round 4
// 1934.399 us; speedup vs baseline: 1.2437x; 1.2437x over previous
//
#include <hip/hip_runtime.h>

#define DEV __device__ __forceinline__

namespace {

typedef __attribute__((ext_vector_type(8))) short short8;
typedef __attribute__((ext_vector_type(4))) float f32x4;

constexpr int B_ = 16, N_ = 4096, S_ = 512, CF_ = 64;
constexpr float EPS_ = 1e-5f;

// ---- ws layout (float units) ----
constexpr int IDX0_OFF  = 0;                    // B*S*32 ints
constexpr int IDX1_OFF  = 262144;               // B*S*64 ints
constexpr int STATS_OFF = IDX1_OFF + 524288;    // 6*256 f
constexpr int AC_OFF    = STATS_OFF + 1536;     // 6*256 f
constexpr int WP_OFF    = AC_OFF + 1536;        // 43008 ushorts = 21504 f
constexpr int MAXT_OFF  = WP_OFF + 21504;       // 8192*128 f
constexpr int FEATT_OFF = MAXT_OFF + 1048576;   // 4194304 ushorts = 2097152 f
constexpr int Y0_OFF    = FEATT_OFF + 2097152;  // up to 33.55M ushorts = 16777216 f
constexpr int Y1_OFF    = Y0_OFF + 16777216;    // up to 50.33M ushorts = 25165824 f
constexpr size_t WS_NEED_FT   = (size_t)Y0_OFF * 4;
constexpr size_t WS_NEED_PIPE = (size_t)(Y1_OFF + 25165824) * 4;

// packed-weight sub-offsets (ushort units)
constexpr int WP00 = 0,     WP01 = 6144,  WP02 = 10240;
constexpr int WP10 = 18432, WP11 = 24576, WP12 = 30720;

DEV int rfl(int x) { return __builtin_amdgcn_readfirstlane(x); }

DEV unsigned short f2bf(float x) {  // RNE float->bf16
  unsigned u = __float_as_uint(x);
  u += 0x7fff + ((u >> 16) & 1);
  return (unsigned short)(u >> 16);
}
DEV float bf2f(unsigned short u) { return __uint_as_float((unsigned)u << 16); }

// ===================== FPS: 256 thr, coords/dists in VGPRs, 1 barrier/iter =====================
__global__ __launch_bounds__(256) void fps_kernel(const float* __restrict__ xyz,
                                                  float* __restrict__ newxyz) {
  __shared__ float px[N_], py[N_], pz[N_];
  __shared__ float swv[2][4];
  __shared__ int   swi[2][4];
  const int b = blockIdx.x, t = threadIdx.x;
  const int lane = t & 63, wv = t >> 6;
  const float* xb = xyz + (size_t)b * N_ * 3;
  for (int i = t; i < N_; i += 256) {
    px[i] = xb[i * 3 + 0];
    py[i] = xb[i * 3 + 1];
    pz[i] = xb[i * 3 + 2];
  }
  __syncthreads();
  // own 16 consecutive points in registers (static unroll only!)
  float X[16], Y[16], Z[16], D[16];
#pragma unroll
  for (int j = 0; j < 16; ++j) {
    X[j] = px[t * 16 + j];
    Y[j] = py[t * 16 + j];
    Z[j] = pz[t * 16 + j];
    D[j] = 1e10f;
  }
  float cx = px[0], cy = py[0], cz = pz[0];
  if (t == 0) {
    newxyz[(size_t)(b * S_) * 3 + 0] = cx;
    newxyz[(size_t)(b * S_) * 3 + 1] = cy;
    newxyz[(size_t)(b * S_) * 3 + 2] = cz;
  }
  for (int it = 1; it < S_; ++it) {
    const int p = it & 1;
    float bv = -1.0f;
    int bi = 0x7fffffff;
#pragma unroll
    for (int j = 0; j < 16; ++j) {
      float d;
      {
#pragma clang fp contract(off)
        float dx = X[j] - cx, dy = Y[j] - cy, dz = Z[j] - cz;
        d = (dx * dx + dy * dy) + dz * dz;
      }
      const float dm = D[j] < d ? D[j] : d;
      D[j] = dm;
      if (dm > bv) { bv = dm; bi = t * 16 + j; }  // j ascending -> lowest index on tie
    }
#pragma unroll
    for (int m = 1; m < 64; m <<= 1) {
      const float ov = __shfl_xor(bv, m);
      const int   oi = __shfl_xor(bi, m);
      if (ov > bv || (ov == bv && oi < bi)) { bv = ov; bi = oi; }
    }
    if (lane == 0) { swv[p][wv] = bv; swi[p][wv] = bi; }
    __syncthreads();
    float rv = swv[p][0];
    int   ri = swi[p][0];
#pragma unroll
    for (int r = 1; r < 4; ++r) {
      const float v = swv[p][r];
      const int   i = swi[p][r];
      if (v > rv || (v == rv && i < ri)) { rv = v; ri = i; }
    }
    cx = px[ri]; cy = py[ri]; cz = pz[ri];
    if (t == 0) {
      newxyz[(size_t)(b * S_ + it) * 3 + 0] = cx;
      newxyz[(size_t)(b * S_ + it) * 3 + 1] = cy;
      newxyz[(size_t)(b * S_ + it) * 3 + 2] = cz;
    }
  }
}

// ===================== Ball query =====================
template <int NS>
__global__ __launch_bounds__(256) void ballq_kernel(const float* __restrict__ xyz,
                                                    const float* __restrict__ newxyz,
                                                    int* __restrict__ idx, float r2) {
  __shared__ int sbuf[4][NS];
  const int wiv = threadIdx.x >> 6;
  const int lane = threadIdx.x & 63;
  const int cs = blockIdx.x * 4 + wiv;
  const int b = cs >> 9;
  const float cx = newxyz[(size_t)cs * 3 + 0];
  const float cy = newxyz[(size_t)cs * 3 + 1];
  const float cz = newxyz[(size_t)cs * 3 + 2];
  const float* xb = xyz + (size_t)b * N_ * 3;
  int* my = sbuf[wiv];
  int cnt = 0;
  for (int base = 0; base < N_; base += 64) {
    if (cnt >= NS) break;
    const int i = base + lane;
    float d;
    {
#pragma clang fp contract(off)
      float dx = xb[i * 3 + 0] - cx, dy = xb[i * 3 + 1] - cy, dz = xb[i * 3 + 2] - cz;
      d = (dx * dx + dy * dy) + dz * dz;
    }
    const bool q = d < r2;
    const unsigned long long m = __ballot(q);
    if (q) {
      int pos = cnt + __popcll(m & ((1ull << lane) - 1ull));
      if (pos < NS) my[pos] = i;
    }
    cnt += __popcll(m);
  }
  __syncthreads();
  const int c = cnt < NS ? cnt : NS;
  const int first = my[0];
  for (int j = lane; j < NS; j += 64) idx[(size_t)cs * NS + j] = (j < c) ? my[j] : first;
}

// ===================== feat transpose to (B,N,64) bf16 =====================
__global__ __launch_bounds__(256) void featT_kernel(const float* __restrict__ feat,
                                                    unsigned short* __restrict__ featT) {
  __shared__ unsigned short tile[64][65];
  const int t = threadIdx.x;
  const int b = blockIdx.x >> 6, nc = blockIdx.x & 63;
  const int n0 = nc * 64;
  for (int i = t; i < 64 * 64; i += 256) {
    int c = i >> 6, n = i & 63;
    tile[c][n] = f2bf(feat[((size_t)b * CF_ + c) * N_ + n0 + n]);
  }
  __syncthreads();
  for (int i = t; i < 64 * 64; i += 256) {
    int n = i >> 6, c = i & 63;
    featT[((size_t)b * N_ + n0 + n) * 64 + c] = tile[c][n];
  }
}

// ===================== weight pack into B-fragment order =====================
__global__ __launch_bounds__(256) void pack_w_kernel(
    const float* __restrict__ w00, const float* __restrict__ w01, const float* __restrict__ w02,
    const float* __restrict__ w10, const float* __restrict__ w11, const float* __restrict__ w12,
    unsigned short* __restrict__ wp) {
  const int id = blockIdx.x * 256 + threadIdx.x;
  const float* w; int off, KK, CINW, base; bool perm;
  if (id < 768)       { w = w00; off = WP00; KK = 3; CINW = 67; perm = true;  base = 0; }
  else if (id < 1280) { w = w01; off = WP01; KK = 2; CINW = 64; perm = false; base = 768; }
  else if (id < 2304) { w = w02; off = WP02; KK = 2; CINW = 64; perm = false; base = 1280; }
  else if (id < 3072) { w = w10; off = WP10; KK = 3; CINW = 67; perm = true;  base = 2304; }
  else if (id < 3840) { w = w11; off = WP11; KK = 2; CINW = 64; perm = false; base = 3072; }
  else if (id < 5376) { w = w12; off = WP12; KK = 3; CINW = 96; perm = false; base = 3840; }
  else return;
  const int lid = id - base;
  const int lane = lid & 63, fr = lid >> 6;
  const int kk = fr % KK, nt = fr / KK;
  const int ccol = nt * 16 + (lane & 15);
  const int kbase = kk * 32 + (lane >> 4) * 8;
  unsigned short* dst = wp + off + (size_t)lid * 8;
#pragma unroll
  for (int j = 0; j < 8; ++j) {
    const int k = kbase + j;
    int cin;
    if (perm) cin = (k < 64) ? k + 3 : (k < 67 ? k - 64 : -1);
    else      cin = (k < CINW) ? k : -1;
    float f = (cin >= 0) ? w[ccol * CINW + cin] : 0.f;
    dst[j] = f2bf(f);
  }
}

// ===================== stats flush helper =====================
template <int DS>
DEV void flush_stats(const float* ssum, const float* ssq, int lane, float* __restrict__ sg) {
  constexpr int NTS = DS / 16;
#pragma unroll
  for (int nt = 0; nt < NTS; ++nt) {
    float s = ssum[nt], q = ssq[nt];
    s += __shfl_xor(s, 16); q += __shfl_xor(q, 16);
    s += __shfl_xor(s, 32); q += __shfl_xor(q, 32);
    if (lane < 16) {
      atomicAdd(&sg[nt * 16 + lane], s);
      atomicAdd(&sg[DS + nt * 16 + lane], q);
    }
  }
}

// ===================== pipeline P1: gather + layer0 (no LDS, no barriers) =====================
template <int K>
__global__ __launch_bounds__(256) void p1_kernel(
    const float* __restrict__ xyz, const unsigned short* __restrict__ featT,
    const float* __restrict__ newxyz, const int* __restrict__ idx,
    const unsigned short* __restrict__ wp0, const float* __restrict__ b0,
    unsigned short* __restrict__ y0, float* __restrict__ stats_out) {
  const int t = threadIdx.x, lane = t & 63;
  const int wid = rfl(t >> 6);
  const int col = lane & 15, khi = lane >> 4;
  constexpr int MT = (B_ * S_ * K) / 16;
  const int w0 = blockIdx.x * 4 + wid;
  short8 bfr[12];
#pragma unroll
  for (int i = 0; i < 12; ++i)
    bfr[i] = *reinterpret_cast<const short8*>(wp0 + ((size_t)i * 64 + lane) * 8);
  float bb[4];
#pragma unroll
  for (int nt = 0; nt < 4; ++nt) bb[nt] = b0[nt * 16 + col];
  float ssum[4] = {0.f, 0.f, 0.f, 0.f}, ssq[4] = {0.f, 0.f, 0.f, 0.f};
  for (int mt = w0; mt < MT; mt += 8192) {
    const int row = mt * 16 + col;
    const int cs = row / K;
    const int b = cs >> 9;
    const int pi = idx[row];
    const unsigned short* fr = featT + (((size_t)b * N_ + pi) << 6);
    const short8 a0 = *reinterpret_cast<const short8*>(fr + khi * 8);
    const short8 a1 = *reinterpret_cast<const short8*>(fr + 32 + khi * 8);
    short8 a2 = {0, 0, 0, 0, 0, 0, 0, 0};
    if (khi == 0) {
      const float* P = xyz + ((size_t)b * N_ + pi) * 3;
      const float* C = newxyz + (size_t)cs * 3;
      a2[0] = (short)f2bf(P[0] - C[0]);
      a2[1] = (short)f2bf(P[1] - C[1]);
      a2[2] = (short)f2bf(P[2] - C[2]);
    }
#pragma unroll
    for (int nt = 0; nt < 4; ++nt) {
      f32x4 a = {0.f, 0.f, 0.f, 0.f};
      a = __builtin_amdgcn_mfma_f32_16x16x32_bf16(a0, bfr[nt * 3 + 0], a, 0, 0, 0);
      a = __builtin_amdgcn_mfma_f32_16x16x32_bf16(a1, bfr[nt * 3 + 1], a, 0, 0, 0);
      a = __builtin_amdgcn_mfma_f32_16x16x32_bf16(a2, bfr[nt * 3 + 2], a, 0, 0, 0);
#pragma unroll
      for (int j = 0; j < 4; ++j) {
        const float y = a[j] + bb[nt];
        ssum[nt] += y; ssq[nt] += y * y;
        y0[(size_t)(mt * 16 + khi * 4 + j) * 64 + nt * 16 + col] = f2bf(y);
      }
    }
  }
  flush_stats<64>(ssum, ssq, lane, stats_out);
}

// ===================== pipeline P2: norm(y_in) -> layer -> y_out =====================
template <int DIN, int DOUT>
__global__ __launch_bounds__(256) void p2_kernel(
    const unsigned short* __restrict__ yin, const unsigned short* __restrict__ wp,
    const float* __restrict__ bias, const float* __restrict__ ac,
    unsigned short* __restrict__ yout, float* __restrict__ stats_out, int MT) {
  constexpr int KK = DIN / 32, NT = DOUT / 16;
  const int t = threadIdx.x, lane = t & 63;
  const int wid = rfl(t >> 6);
  const int col = lane & 15, khi = lane >> 4;
  const int w0 = blockIdx.x * 4 + wid;
  short8 bfr[NT * KK];
#pragma unroll
  for (int i = 0; i < NT * KK; ++i)
    bfr[i] = *reinterpret_cast<const short8*>(wp + ((size_t)i * 64 + lane) * 8);
  float bb[NT];
#pragma unroll
  for (int nt = 0; nt < NT; ++nt) bb[nt] = bias[nt * 16 + col];
  float ar[KK][8], cr[KK][8];
#pragma unroll
  for (int kk = 0; kk < KK; ++kk)
#pragma unroll
    for (int j = 0; j < 8; ++j) {
      const int ch = kk * 32 + khi * 8 + j;
      ar[kk][j] = ac[ch];
      cr[kk][j] = ac[DIN + ch];
    }
  float ssum[NT], ssq[NT];
#pragma unroll
  for (int nt = 0; nt < NT; ++nt) { ssum[nt] = 0.f; ssq[nt] = 0.f; }
  for (int mt = w0; mt < MT; mt += 8192) {
    const size_t rb = (size_t)(mt * 16 + col) * DIN;
    short8 af[KK];
#pragma unroll
    for (int kk = 0; kk < KK; ++kk) {
      const short8 raw = *reinterpret_cast<const short8*>(yin + rb + kk * 32 + khi * 8);
#pragma unroll
      for (int j = 0; j < 8; ++j) {
        const float v = bf2f((unsigned short)raw[j]) * ar[kk][j] + cr[kk][j];
        af[kk][j] = (short)f2bf(fmaxf(v, 0.f));
      }
    }
#pragma unroll
    for (int nt = 0; nt < NT; ++nt) {
      f32x4 a = {0.f, 0.f, 0.f, 0.f};
#pragma unroll
      for (int kk = 0; kk < KK; ++kk)
        a = __builtin_amdgcn_mfma_f32_16x16x32_bf16(af[kk], bfr[nt * KK + kk], a, 0, 0, 0);
#pragma unroll
      for (int j = 0; j < 4; ++j) {
        const float y = a[j] + bb[nt];
        ssum[nt] += y; ssq[nt] += y * y;
        yout[(size_t)(mt * 16 + khi * 4 + j) * DOUT + nt * 16 + col] = f2bf(y);
      }
    }
  }
  flush_stats<DOUT>(ssum, ssq, lane, stats_out);
}

// ===================== pipeline P3: norm(y1) -> layer2 -> stats + k-max =====================
template <int DIN, int K>
__global__ __launch_bounds__(256) void p3_kernel(
    const unsigned short* __restrict__ yin, const unsigned short* __restrict__ wp,
    const float* __restrict__ bias, const float* __restrict__ ac,
    float* __restrict__ maxtmp, float* __restrict__ stats_out) {
  constexpr int KK = DIN / 32, NT = 8;
  const int t = threadIdx.x, lane = t & 63;
  const int wid = rfl(t >> 6);
  const int col = lane & 15, khi = lane >> 4;
  const int c = blockIdx.x * 4 + wid;  // 8192 waves == 8192 centers
  short8 bfr[NT * KK];
#pragma unroll
  for (int i = 0; i < NT * KK; ++i)
    bfr[i] = *reinterpret_cast<const short8*>(wp + ((size_t)i * 64 + lane) * 8);
  float bb[NT];
#pragma unroll
  for (int nt = 0; nt < NT; ++nt) bb[nt] = bias[nt * 16 + col];
  float ar[KK][8], cr[KK][8];
#pragma unroll
  for (int kk = 0; kk < KK; ++kk)
#pragma unroll
    for (int j = 0; j < 8; ++j) {
      const int ch = kk * 32 + khi * 8 + j;
      ar[kk][j] = ac[ch];
      cr[kk][j] = ac[DIN + ch];
    }
  float ssum[NT], ssq[NT], mx[NT];
#pragma unroll
  for (int nt = 0; nt < NT; ++nt) { ssum[nt] = 0.f; ssq[nt] = 0.f; mx[nt] = -3.4e38f; }
#pragma unroll
  for (int m = 0; m < K / 16; ++m) {
    const size_t rb = (size_t)(c * K + m * 16 + col) * DIN;
    short8 af[KK];
#pragma unroll
    for (int kk = 0; kk < KK; ++kk) {
      const short8 raw = *reinterpret_cast<const short8*>(yin + rb + kk * 32 + khi * 8);
#pragma unroll
      for (int j = 0; j < 8; ++j) {
        const float v = bf2f((unsigned short)raw[j]) * ar[kk][j] + cr[kk][j];
        af[kk][j] = (short)f2bf(fmaxf(v, 0.f));
      }
    }
#pragma unroll
    for (int nt = 0; nt < NT; ++nt) {
      f32x4 a = {0.f, 0.f, 0.f, 0.f};
#pragma unroll
      for (int kk = 0; kk < KK; ++kk)
        a = __builtin_amdgcn_mfma_f32_16x16x32_bf16(af[kk], bfr[nt * KK + kk], a, 0, 0, 0);
#pragma unroll
      for (int j = 0; j < 4; ++j) {
        const float y = a[j] + bb[nt];
        ssum[nt] += y; ssq[nt] += y * y;
        mx[nt] = fmaxf(mx[nt], y);
      }
    }
  }
#pragma unroll
  for (int nt = 0; nt < NT; ++nt) {
    mx[nt] = fmaxf(mx[nt], __shfl_xor(mx[nt], 16));
    mx[nt] = fmaxf(mx[nt], __shfl_xor(mx[nt], 32));
  }
  if (lane < 16) {
#pragma unroll
    for (int nt = 0; nt < NT; ++nt) maxtmp[(size_t)c * 128 + nt * 16 + lane] = mx[nt];
  }
  flush_stats<128>(ssum, ssq, lane, stats_out);
}

// ===================== fallback path (round-2 stage_mfma) =====================
template <int K, bool FT>
DEV void gather_tile(unsigned short* sX, const float* __restrict__ xyz,
                     const float* __restrict__ feat, const unsigned short* __restrict__ featT,
                     const float* __restrict__ newxyz, const int* __restrict__ idx, int tile) {
  const int t = threadIdx.x, r = t & 63, c4 = t >> 6;
  const int rep = r / K, k = r % K;
  const int cs = tile * (64 / K) + rep, b = cs >> 9;
  const int pi = idx[(size_t)cs * K + k];
  unsigned short* dst = sX + r * 104;
  if (FT) {
    const unsigned short* src = featT + (((size_t)b * N_ + pi) << 6) + c4 * 16;
    *reinterpret_cast<short8*>(dst + c4 * 16)     = *reinterpret_cast<const short8*>(src);
    *reinterpret_cast<short8*>(dst + c4 * 16 + 8) = *reinterpret_cast<const short8*>(src + 8);
  } else {
#pragma unroll
    for (int j = 0; j < 16; ++j) {
      const int ch = c4 * 16 + j;
      dst[ch] = f2bf(feat[((size_t)b * CF_ + ch) * N_ + pi]);
    }
  }
  if (c4 == 0) {
    const float* P = xyz + ((size_t)b * N_ + pi) * 3;
    const float* C = newxyz + (size_t)cs * 3;
    dst[64] = f2bf(P[0] - C[0]);
    dst[65] = f2bf(P[1] - C[1]);
    dst[66] = f2bf(P[2] - C[2]);
  }
}

template <int NTILES, int KK>
DEV void layer_mfma(const unsigned short* sIn, int stride, const unsigned short* __restrict__ wp,
                    int lane, int wid, f32x4* acc) {
  short8 af[KK];
  const int arow = wid * 16 + (lane & 15);
  const int kof = (lane >> 4) * 8;
#pragma unroll
  for (int kk = 0; kk < KK; ++kk)
    af[kk] = *reinterpret_cast<const short8*>(sIn + arow * stride + kk * 32 + kof);
#pragma unroll
  for (int nt = 0; nt < NTILES; ++nt) {
    f32x4 a = {0.f, 0.f, 0.f, 0.f};
#pragma unroll
    for (int kk = 0; kk < KK; ++kk) {
      short8 bf = *reinterpret_cast<const short8*>(wp + ((size_t)(nt * KK + kk) * 64 + lane) * 8);
      a = __builtin_amdgcn_mfma_f32_16x16x32_bf16(af[kk], bf, a, 0, 0, 0);
    }
    acc[nt] = a;
  }
}

template <int K, int D0, int D1, int D2, int STAGE, bool FT>
__global__ __launch_bounds__(256) void stage_mfma(
    const float* __restrict__ xyz, const float* __restrict__ feat,
    const unsigned short* __restrict__ featT, const float* __restrict__ newxyz,
    const int* __restrict__ idx,
    const unsigned short* __restrict__ wp0, const unsigned short* __restrict__ wp1,
    const unsigned short* __restrict__ wp2,
    const float* __restrict__ b0, const float* __restrict__ b1, const float* __restrict__ b2,
    const float* __restrict__ ac0, const float* __restrict__ ac1,
    float* __restrict__ stats_out, float* __restrict__ maxtmp) {
  constexpr int CPB = 64 / K, NT = (B_ * S_) / CPB;
  constexpr int ST0 = 104, ST1 = 72, ST2 = (D1 == 96) ? 104 : 72;
  constexpr int KK0 = 3, KK1 = D0 / 32, KK2 = D1 / 32;
  constexpr int NT0 = D0 / 16, NT1 = D1 / 16, NT2 = D2 / 16;
  constexpr int DS = (STAGE == 1) ? D0 : (STAGE == 2) ? D1 : D2;
  constexpr int NTS = DS / 16;

  __shared__ unsigned short sX[64 * ST0];
  __shared__ unsigned short sY0[(STAGE >= 2) ? 64 * ST1 : 8];
  __shared__ unsigned short sY1[(STAGE == 3) ? 64 * ST2 : 8];
  __shared__ float smax[(STAGE == 3) ? 512 : 4];

  const int t = threadIdx.x, lane = t & 63;
  const int wid = rfl(t >> 6);
  const int col = lane & 15, khi = lane >> 4;

  for (int i = t; i < 64 * 37; i += 256) sX[(i / 37) * ST0 + 67 + (i % 37)] = 0;

  float b0r[NT0], a0r[NT0], c0r[NT0];
  float b1r[NT1], a1r[NT1], c1r[NT1];
  float b2r[NT2];
#pragma unroll
  for (int nt = 0; nt < NT0; ++nt) {
    b0r[nt] = b0[nt * 16 + col];
    if constexpr (STAGE >= 2) {
      a0r[nt] = ac0[nt * 16 + col];
      c0r[nt] = ac0[D0 + nt * 16 + col];
    }
  }
  if constexpr (STAGE >= 2) {
#pragma unroll
    for (int nt = 0; nt < NT1; ++nt) {
      b1r[nt] = b1[nt * 16 + col];
      if constexpr (STAGE == 3) {
        a1r[nt] = ac1[nt * 16 + col];
        c1r[nt] = ac1[D1 + nt * 16 + col];
      }
    }
  }
  if constexpr (STAGE == 3) {
#pragma unroll
    for (int nt = 0; nt < NT2; ++nt) b2r[nt] = b2[nt * 16 + col];
  }

  float ssum[NTS], ssq[NTS];
#pragma unroll
  for (int nt = 0; nt < NTS; ++nt) { ssum[nt] = 0.f; ssq[nt] = 0.f; }

  for (int tile = blockIdx.x; tile < NT; tile += gridDim.x) {
    __syncthreads();
    gather_tile<K, FT>(sX, xyz, feat, featT, newxyz, idx, tile);
    __syncthreads();

    f32x4 acc0[NT0];
    layer_mfma<NT0, KK0>(sX, ST0, wp0, lane, wid, acc0);
    if constexpr (STAGE == 1) {
#pragma unroll
      for (int nt = 0; nt < NT0; ++nt) {
        const float bb = b0r[nt];
#pragma unroll
        for (int j = 0; j < 4; ++j) {
          const float y = acc0[nt][j] + bb;
          ssum[nt] += y; ssq[nt] += y * y;
        }
      }
    } else {
#pragma unroll
      for (int nt = 0; nt < NT0; ++nt) {
#pragma unroll
        for (int j = 0; j < 4; ++j) {
          float y = (acc0[nt][j] + b0r[nt]) * a0r[nt] + c0r[nt];
          y = fmaxf(y, 0.f);
          sY0[(wid * 16 + khi * 4 + j) * ST1 + nt * 16 + col] = f2bf(y);
        }
      }
      __syncthreads();
      f32x4 acc1[NT1];
      layer_mfma<NT1, KK1>(sY0, ST1, wp1, lane, wid, acc1);
      if constexpr (STAGE == 2) {
#pragma unroll
        for (int nt = 0; nt < NT1; ++nt) {
          const float bb = b1r[nt];
#pragma unroll
          for (int j = 0; j < 4; ++j) {
            const float y = acc1[nt][j] + bb;
            ssum[nt] += y; ssq[nt] += y * y;
          }
        }
      } else {
#pragma unroll
        for (int nt = 0; nt < NT1; ++nt) {
#pragma unroll
          for (int j = 0; j < 4; ++j) {
            float y = (acc1[nt][j] + b1r[nt]) * a1r[nt] + c1r[nt];
            y = fmaxf(y, 0.f);
            sY1[(wid * 16 + khi * 4 + j) * ST2 + nt * 16 + col] = f2bf(y);
          }
        }
        __syncthreads();
        f32x4 acc2[NT2];
        layer_mfma<NT2, KK2>(sY1, ST2, wp2, lane, wid, acc2);
#pragma unroll
        for (int nt = 0; nt < NT2; ++nt) {
          const float bb = b2r[nt];
          const float y0 = acc2[nt][0] + bb, y1 = acc2[nt][1] + bb;
          const float y2 = acc2[nt][2] + bb, y3 = acc2[nt][3] + bb;
          ssum[nt] += (y0 + y1) + (y2 + y3);
          ssq[nt] += (y0 * y0 + y1 * y1) + (y2 * y2 + y3 * y3);
          float m = fmaxf(fmaxf(y0, y1), fmaxf(y2, y3));
          m = fmaxf(m, __shfl_xor(m, 16));
          m = fmaxf(m, __shfl_xor(m, 32));
          if (lane < 16) smax[wid * 128 + nt * 16 + lane] = m;
        }
        __syncthreads();
        if constexpr (K == 64) {
          if (t < 128) {
            const float m = fmaxf(fmaxf(smax[t], smax[128 + t]), fmaxf(smax[256 + t], smax[384 + t]));
            maxtmp[(size_t)tile * 128 + t] = m;
          }
        } else {
          const int ce = t >> 7, ch = t & 127;
          const float m = fmaxf(smax[ce * 256 + ch], smax[ce * 256 + 128 + ch]);
          maxtmp[((size_t)(tile * 2 + ce)) * 128 + ch] = m;
        }
      }
    }
  }
  flush_stats<DS>(ssum, ssq, lane, stats_out);
}

__global__ void finalize_kernel(const float* __restrict__ stats, const float* __restrict__ g,
                                const float* __restrict__ beta, float* __restrict__ ac,
                                float n, int cout) {
  const int t = threadIdx.x;
  if (t < cout) {
    const float mu = stats[t] / n;
    const float var = stats[cout + t] / n - mu * mu;
    const float a = g[t] / sqrtf(var + EPS_);
    ac[t] = a;
    ac[cout + t] = beta[t] - mu * a;
  }
}

__global__ __launch_bounds__(256) void out_kernel(const float* __restrict__ maxtmp,
                                                  const float* __restrict__ ac2,
                                                  float* __restrict__ outf, int coff) {
  const int i = blockIdx.x * 256 + threadIdx.x;
  if (i >= B_ * 128 * S_) return;
  const int s = i & 511;
  const int o = (i >> 9) & 127;
  const int b = i >> 16;
  const float a = ac2[o], c = ac2[128 + o];
  const float v = maxtmp[((size_t)(b * S_ + s)) * 128 + o];
  outf[((size_t)b * 256 + coff + o) * S_ + s] = a * v + c;
}

}  // namespace

extern "C" void kernel_launch(void* const* d_in, const int* in_sizes, int n_in,
                              void* d_out, int out_size, void* d_ws, size_t ws_size,
                              hipStream_t stream) {
  const float* xyz  = (const float*)d_in[0];
  const float* feat = (const float*)d_in[1];
  const float* w00 = (const float*)d_in[2];  const float* b00 = (const float*)d_in[3];
  const float* g00 = (const float*)d_in[4];  const float* be00 = (const float*)d_in[5];
  const float* w01 = (const float*)d_in[6];  const float* b01 = (const float*)d_in[7];
  const float* g01 = (const float*)d_in[8];  const float* be01 = (const float*)d_in[9];
  const float* w02 = (const float*)d_in[10]; const float* b02 = (const float*)d_in[11];
  const float* g02 = (const float*)d_in[12]; const float* be02 = (const float*)d_in[13];
  const float* w10 = (const float*)d_in[14]; const float* b10 = (const float*)d_in[15];
  const float* g10 = (const float*)d_in[16]; const float* be10 = (const float*)d_in[17];
  const float* w11 = (const float*)d_in[18]; const float* b11 = (const float*)d_in[19];
  const float* g11 = (const float*)d_in[20]; const float* be11 = (const float*)d_in[21];
  const float* w12 = (const float*)d_in[22]; const float* b12 = (const float*)d_in[23];
  const float* g12 = (const float*)d_in[24]; const float* be12 = (const float*)d_in[25];

  float* ws = (float*)d_ws;
  int* idx0 = (int*)(ws + IDX0_OFF);
  int* idx1 = (int*)(ws + IDX1_OFF);
  float* stats = ws + STATS_OFF;
  float* ac = ws + AC_OFF;
  unsigned short* wp = (unsigned short*)(ws + WP_OFF);
  float* maxtmp = ws + MAXT_OFF;
  unsigned short* featT = (unsigned short*)(ws + FEATT_OFF);
  unsigned short* y0us = (unsigned short*)(ws + Y0_OFF);
  unsigned short* y1us = (unsigned short*)(ws + Y1_OFF);

  const bool usePipe = ws_size >= WS_NEED_PIPE;
  const bool useFT   = ws_size >= WS_NEED_FT;

  float* outF = (float*)d_out;          // new_xyz (B,S,3)
  float* outFeat = outF + B_ * S_ * 3;  // (B,256,S)

  hipMemsetAsync(stats, 0, 6 * 256 * sizeof(float), stream);
  pack_w_kernel<<<21, 256, 0, stream>>>(w00, w01, w02, w10, w11, w12, wp);
  if (useFT) featT_kernel<<<1024, 256, 0, stream>>>(feat, featT);
  fps_kernel<<<16, 256, 0, stream>>>(xyz, outF);
  ballq_kernel<32><<<2048, 256, 0, stream>>>(xyz, outF, idx0, 0.2f * 0.2f);
  ballq_kernel<64><<<2048, 256, 0, stream>>>(xyz, outF, idx1, 0.4f * 0.4f);

  const float n0 = (float)(B_ * S_ * 32);
  const float n1 = (float)(B_ * S_ * 64);

  if (usePipe) {
    // ---- scale 0: K=32, 67->64->64->128, rows = 262144 ----
    p1_kernel<32><<<2048, 256, 0, stream>>>(xyz, featT, outF, idx0, wp + WP00, b00,
                                            y0us, stats + 0 * 256);
    finalize_kernel<<<1, 128, 0, stream>>>(stats + 0 * 256, g00, be00, ac + 0 * 256, n0, 64);
    p2_kernel<64, 64><<<2048, 256, 0, stream>>>(y0us, wp + WP01, b01, ac + 0 * 256,
                                                y1us, stats + 1 * 256, 16384);
    finalize_kernel<<<1, 128, 0, stream>>>(stats + 1 * 256, g01, be01, ac + 1 * 256, n0, 64);
    p3_kernel<64, 32><<<2048, 256, 0, stream>>>(y1us, wp + WP02, b02, ac + 1 * 256,
                                                maxtmp, stats + 2 * 256);
    finalize_kernel<<<1, 128, 0, stream>>>(stats + 2 * 256, g02, be02, ac + 2 * 256, n0, 128);
    out_kernel<<<4096, 256, 0, stream>>>(maxtmp, ac + 2 * 256, outFeat, 0);

    // ---- scale 1: K=64, 67->64->96->128, rows = 524288 ----
    p1_kernel<64><<<2048, 256, 0, stream>>>(xyz, featT, outF, idx1, wp + WP10, b10,
                                            y0us, stats + 3 * 256);
    finalize_kernel<<<1, 128, 0, stream>>>(stats + 3 * 256, g10, be10, ac + 3 * 256, n1, 64);
    p2_kernel<64, 96><<<2048, 256, 0, stream>>>(y0us, wp + WP11, b11, ac + 3 * 256,
                                                y1us, stats + 4 * 256, 32768);
    finalize_kernel<<<1, 128, 0, stream>>>(stats + 4 * 256, g11, be11, ac + 4 * 256, n1, 96);
    p3_kernel<96, 64><<<2048, 256, 0, stream>>>(y1us, wp + WP12, b12, ac + 4 * 256,
                                                maxtmp, stats + 5 * 256);
    finalize_kernel<<<1, 128, 0, stream>>>(stats + 5 * 256, g12, be12, ac + 5 * 256, n1, 128);
    out_kernel<<<4096, 256, 0, stream>>>(maxtmp, ac + 5 * 256, outFeat, 128);
    return;
  }

#define LAUNCH_SCALE0(STG)                                                              \
  do {                                                                                  \
    if (useFT)                                                                          \
      stage_mfma<32, 64, 64, 128, STG, true><<<2048, 256, 0, stream>>>(                 \
          xyz, feat, featT, outF, idx0, wp + WP00, wp + WP01, wp + WP02, b00, b01, b02, \
          ac + 0 * 256, ac + 1 * 256, stats + (STG - 1) * 256, maxtmp);                 \
    else                                                                                \
      stage_mfma<32, 64, 64, 128, STG, false><<<2048, 256, 0, stream>>>(                \
          xyz, feat, featT, outF, idx0, wp + WP00, wp + WP01, wp + WP02, b00, b01, b02, \
          ac + 0 * 256, ac + 1 * 256, stats + (STG - 1) * 256, maxtmp);                 \
  } while (0)
#define LAUNCH_SCALE1(STG)                                                              \
  do {                                                                                  \
    if (useFT)                                                                          \
      stage_mfma<64, 64, 96, 128, STG, true><<<2048, 256, 0, stream>>>(                 \
          xyz, feat, featT, outF, idx1, wp + WP10, wp + WP11, wp + WP12, b10, b11, b12, \
          ac + 3 * 256, ac + 4 * 256, stats + (2 + STG) * 256, maxtmp);                 \
    else                                                                                \
      stage_mfma<64, 64, 96, 128, STG, false><<<2048, 256, 0, stream>>>(                \
          xyz, feat, featT, outF, idx1, wp + WP10, wp + WP11, wp + WP12, b10, b11, b12, \
          ac + 3 * 256, ac + 4 * 256, stats + (2 + STG) * 256, maxtmp);                 \
  } while (0)

  LAUNCH_SCALE0(1);
  finalize_kernel<<<1, 128, 0, stream>>>(stats + 0 * 256, g00, be00, ac + 0 * 256, n0, 64);
  LAUNCH_SCALE0(2);
  finalize_kernel<<<1, 128, 0, stream>>>(stats + 1 * 256, g01, be01, ac + 1 * 256, n0, 64);
  LAUNCH_SCALE0(3);
  finalize_kernel<<<1, 128, 0, stream>>>(stats + 2 * 256, g02, be02, ac + 2 * 256, n0, 128);
  out_kernel<<<4096, 256, 0, stream>>>(maxtmp, ac + 2 * 256, outFeat, 0);

  LAUNCH_SCALE1(1);
  finalize_kernel<<<1, 128, 0, stream>>>(stats + 3 * 256, g10, be10, ac + 3 * 256, n1, 64);
  LAUNCH_SCALE1(2);
  finalize_kernel<<<1, 128, 0, stream>>>(stats + 4 * 256, g11, be11, ac + 4 * 256, n1, 96);
  LAUNCH_SCALE1(3);
  finalize_kernel<<<1, 128, 0, stream>>>(stats + 5 * 256, g12, be12, ac + 5 * 256, n1, 128);
  out_kernel<<<4096, 256, 0, stream>>>(maxtmp, ac + 5 * 256, outFeat, 128);

#undef LAUNCH_SCALE0
#undef LAUNCH_SCALE1
}

// Round 5
// 1724.320 us; speedup vs baseline: 1.3952x; 1.1218x over previous
//
#include <hip/hip_runtime.h>

#define DEV __device__ __forceinline__

namespace {

typedef __attribute__((ext_vector_type(8))) short short8;
typedef __attribute__((ext_vector_type(4))) float f32x4;

constexpr int B_ = 16, N_ = 4096, S_ = 512, CF_ = 64;
constexpr float EPS_ = 1e-5f;

// ---- ws layout (float units) ----
constexpr int IDX0_OFF  = 0;                    // B*S*32 ints
constexpr int IDX1_OFF  = 262144;               // B*S*64 ints
constexpr int STATS_OFF = IDX1_OFF + 524288;    // 6*256 f
constexpr int AC_OFF    = STATS_OFF + 1536;     // 6*256 f (fallback only)
constexpr int WP_OFF    = AC_OFF + 1536;        // 43008 ushorts = 21504 f
constexpr int MAXT_OFF  = WP_OFF + 21504;       // 8192*128 f
constexpr int FEATT_OFF = MAXT_OFF + 1048576;   // 4194304 ushorts = 2097152 f
constexpr int Y0_OFF    = FEATT_OFF + 2097152;  // 16777216 f
constexpr int Y1_OFF    = Y0_OFF + 16777216;    // 25165824 f
constexpr size_t WS_NEED_FT   = (size_t)Y0_OFF * 4;
constexpr size_t WS_NEED_PIPE = (size_t)(Y1_OFF + 25165824) * 4;

// packed-weight sub-offsets (ushort units)
constexpr int WP00 = 0,     WP01 = 6144,  WP02 = 10240;
constexpr int WP10 = 18432, WP11 = 24576, WP12 = 30720;

DEV int rfl(int x) { return __builtin_amdgcn_readfirstlane(x); }

DEV unsigned short f2bf(float x) {  // RNE float->bf16
  unsigned u = __float_as_uint(x);
  u += 0x7fff + ((u >> 16) & 1);
  return (unsigned short)(u >> 16);
}
DEV float bf2f(unsigned short u) { return __uint_as_float((unsigned)u << 16); }

// ===================== FPS: no global stores in loop; u64 argmax keys =====================
__global__ __launch_bounds__(256) void fps_kernel(const float* __restrict__ xyz,
                                                  float* __restrict__ newxyz) {
  __shared__ float px[N_], py[N_], pz[N_];
  __shared__ unsigned long long swk[2][4];
  __shared__ int seq[S_];
  const int b = blockIdx.x, t = threadIdx.x;
  const int lane = t & 63, wv = t >> 6;
  const float* xb = xyz + (size_t)b * N_ * 3;
  for (int i = t; i < N_; i += 256) {
    px[i] = xb[i * 3 + 0];
    py[i] = xb[i * 3 + 1];
    pz[i] = xb[i * 3 + 2];
  }
  __syncthreads();
  float X[16], Y[16], Z[16], D[16];
#pragma unroll
  for (int j = 0; j < 16; ++j) {
    X[j] = px[t * 16 + j];
    Y[j] = py[t * 16 + j];
    Z[j] = pz[t * 16 + j];
    D[j] = 1e10f;
  }
  float cx = px[0], cy = py[0], cz = pz[0];
  if (t == 0) seq[0] = 0;
  for (int it = 1; it < S_; ++it) {
    const int p = it & 1;
    float bv = -1.0f;
    int bi = 0x7fffffff;
#pragma unroll
    for (int j = 0; j < 16; ++j) {
      float d;
      {
#pragma clang fp contract(off)
        float dx = X[j] - cx, dy = Y[j] - cy, dz = Z[j] - cz;
        d = (dx * dx + dy * dy) + dz * dz;
      }
      const float dm = D[j] < d ? D[j] : d;
      D[j] = dm;
      if (dm > bv) { bv = dm; bi = t * 16 + j; }  // strict > keeps lowest index
    }
    // bv >= 0 here, so IEEE bits order == value order; tie -> max(~bi) == min(bi)
    unsigned long long k =
        ((unsigned long long)__float_as_uint(bv) << 32) | (unsigned)(~bi);
#pragma unroll
    for (int m = 1; m < 64; m <<= 1) {
      const unsigned long long ok = __shfl_xor(k, m);
      if (ok > k) k = ok;
    }
    if (lane == 0) swk[p][wv] = k;
    __syncthreads();
    const unsigned long long k0 = swk[p][0], k1 = swk[p][1];
    const unsigned long long k2 = swk[p][2], k3 = swk[p][3];
    const unsigned long long ka = k0 > k1 ? k0 : k1;
    const unsigned long long kb = k2 > k3 ? k2 : k3;
    const unsigned long long kw = ka > kb ? ka : kb;
    const int ri = (int)(~(unsigned)kw);
    cx = px[ri]; cy = py[ri]; cz = pz[ri];
    if (t == 0) seq[it] = ri;
  }
  __syncthreads();
  for (int i = t; i < S_; i += 256) {
    const int ri = seq[i];
    newxyz[(size_t)(b * S_ + i) * 3 + 0] = px[ri];
    newxyz[(size_t)(b * S_ + i) * 3 + 1] = py[ri];
    newxyz[(size_t)(b * S_ + i) * 3 + 2] = pz[ri];
  }
}

// ===================== Ball query (both scales in one launch) =====================
__global__ __launch_bounds__(256) void ballq_both(const float* __restrict__ xyz,
                                                  const float* __restrict__ newxyz,
                                                  int* __restrict__ idx0,
                                                  int* __restrict__ idx1) {
  __shared__ int sbuf[4][64];
  const int blk = blockIdx.x;
  const int scale = blk >> 11;
  const int cb = blk & 2047;
  const int NS = scale ? 64 : 32;
  const float r2 = scale ? 0.4f * 0.4f : 0.2f * 0.2f;
  int* __restrict__ idx = scale ? idx1 : idx0;
  const int wiv = threadIdx.x >> 6;
  const int lane = threadIdx.x & 63;
  const int cs = cb * 4 + wiv;
  const int b = cs >> 9;
  const float cx = newxyz[(size_t)cs * 3 + 0];
  const float cy = newxyz[(size_t)cs * 3 + 1];
  const float cz = newxyz[(size_t)cs * 3 + 2];
  const float* xb = xyz + (size_t)b * N_ * 3;
  int* my = sbuf[wiv];
  int cnt = 0;
  for (int base = 0; base < N_; base += 64) {
    if (cnt >= NS) break;
    const int i = base + lane;
    float d;
    {
#pragma clang fp contract(off)
      float dx = xb[i * 3 + 0] - cx, dy = xb[i * 3 + 1] - cy, dz = xb[i * 3 + 2] - cz;
      d = (dx * dx + dy * dy) + dz * dz;
    }
    const bool q = d < r2;
    const unsigned long long m = __ballot(q);
    if (q) {
      int pos = cnt + __popcll(m & ((1ull << lane) - 1ull));
      if (pos < NS) my[pos] = i;
    }
    cnt += __popcll(m);
  }
  __syncthreads();
  const int c = cnt < NS ? cnt : NS;
  const int first = my[0];
  for (int j = lane; j < NS; j += 64) idx[(size_t)cs * NS + j] = (j < c) ? my[j] : first;
}

// ===================== prep: stats zero + weight pack + feat transpose =====================
__global__ __launch_bounds__(256) void prep_kernel(
    const float* __restrict__ feat, unsigned short* __restrict__ featT, int doFT,
    const float* __restrict__ w00, const float* __restrict__ w01, const float* __restrict__ w02,
    const float* __restrict__ w10, const float* __restrict__ w11, const float* __restrict__ w12,
    unsigned short* __restrict__ wp, float* __restrict__ stats) {
  const int blk = blockIdx.x, t = threadIdx.x;
  if (blk == 0) {
    for (int i = t; i < 1536; i += 256) stats[i] = 0.f;
  }
  {  // weight pack (blocks 0..20)
    const int id = blk * 256 + t;
    const float* w = nullptr; int off = 0, KK = 0, CINW = 0, base = 0; bool perm = false;
    if (id < 768)       { w = w00; off = WP00; KK = 3; CINW = 67; perm = true;  base = 0; }
    else if (id < 1280) { w = w01; off = WP01; KK = 2; CINW = 64; perm = false; base = 768; }
    else if (id < 2304) { w = w02; off = WP02; KK = 2; CINW = 64; perm = false; base = 1280; }
    else if (id < 3072) { w = w10; off = WP10; KK = 3; CINW = 67; perm = true;  base = 2304; }
    else if (id < 3840) { w = w11; off = WP11; KK = 2; CINW = 64; perm = false; base = 3072; }
    else if (id < 5376) { w = w12; off = WP12; KK = 3; CINW = 96; perm = false; base = 3840; }
    if (w) {
      const int lid = id - base;
      const int lane = lid & 63, fr = lid >> 6;
      const int kk = fr % KK, nt = fr / KK;
      const int ccol = nt * 16 + (lane & 15);
      const int kbase = kk * 32 + (lane >> 4) * 8;
      unsigned short* dst = wp + off + (size_t)lid * 8;
#pragma unroll
      for (int j = 0; j < 8; ++j) {
        const int k = kbase + j;
        int cin;
        if (perm) cin = (k < 64) ? k + 3 : (k < 67 ? k - 64 : -1);
        else      cin = (k < CINW) ? k : -1;
        float f = (cin >= 0) ? w[ccol * CINW + cin] : 0.f;
        dst[j] = f2bf(f);
      }
    }
  }
  if (doFT) {  // feat transpose, 1024 blocks
    __shared__ unsigned short tile[64][65];
    const int b = blk >> 6, nc = blk & 63;
    const int n0 = nc * 64;
    for (int i = t; i < 64 * 64; i += 256) {
      int c = i >> 6, n = i & 63;
      tile[c][n] = f2bf(feat[((size_t)b * CF_ + c) * N_ + n0 + n]);
    }
    __syncthreads();
    for (int i = t; i < 64 * 64; i += 256) {
      int n = i >> 6, c = i & 63;
      featT[((size_t)b * N_ + n0 + n) * 64 + c] = tile[c][n];
    }
  }
}

// ===================== stats flush helper =====================
template <int DS>
DEV void flush_stats(const float* ssum, const float* ssq, int lane, float* __restrict__ sg) {
  constexpr int NTS = DS / 16;
#pragma unroll
  for (int nt = 0; nt < NTS; ++nt) {
    float s = ssum[nt], q = ssq[nt];
    s += __shfl_xor(s, 16); q += __shfl_xor(q, 16);
    s += __shfl_xor(s, 32); q += __shfl_xor(q, 32);
    if (lane < 16) {
      atomicAdd(&sg[nt * 16 + lane], s);
      atomicAdd(&sg[DS + nt * 16 + lane], q);
    }
  }
}

// ===================== pipeline P1: gather + layer0 =====================
template <int K>
__global__ __launch_bounds__(256) void p1_kernel(
    const float* __restrict__ xyz, const unsigned short* __restrict__ featT,
    const float* __restrict__ newxyz, const int* __restrict__ idx,
    const unsigned short* __restrict__ wp0, const float* __restrict__ b0,
    unsigned short* __restrict__ y0, float* __restrict__ stats_out) {
  const int t = threadIdx.x, lane = t & 63;
  const int col = lane & 15, khi = lane >> 4;
  const int wid = rfl(t >> 6);
  constexpr int MT = (B_ * S_ * K) / 16;
  const int w0 = blockIdx.x * 4 + wid;
  short8 bfr[12];
#pragma unroll
  for (int i = 0; i < 12; ++i)
    bfr[i] = *reinterpret_cast<const short8*>(wp0 + ((size_t)i * 64 + lane) * 8);
  float bb[4];
#pragma unroll
  for (int nt = 0; nt < 4; ++nt) bb[nt] = b0[nt * 16 + col];
  float ssum[4] = {0.f, 0.f, 0.f, 0.f}, ssq[4] = {0.f, 0.f, 0.f, 0.f};
  for (int mt = w0; mt < MT; mt += 8192) {
    const int row = mt * 16 + col;
    const int cs = row / K;
    const int b = cs >> 9;
    const int pi = idx[row];
    const unsigned short* fr = featT + (((size_t)b * N_ + pi) << 6);
    const short8 a0 = *reinterpret_cast<const short8*>(fr + khi * 8);
    const short8 a1 = *reinterpret_cast<const short8*>(fr + 32 + khi * 8);
    short8 a2 = {0, 0, 0, 0, 0, 0, 0, 0};
    if (khi == 0) {
      const float* P = xyz + ((size_t)b * N_ + pi) * 3;
      const float* C = newxyz + (size_t)cs * 3;
      a2[0] = (short)f2bf(P[0] - C[0]);
      a2[1] = (short)f2bf(P[1] - C[1]);
      a2[2] = (short)f2bf(P[2] - C[2]);
    }
#pragma unroll
    for (int nt = 0; nt < 4; ++nt) {
      f32x4 a = {0.f, 0.f, 0.f, 0.f};
      a = __builtin_amdgcn_mfma_f32_16x16x32_bf16(a0, bfr[nt * 3 + 0], a, 0, 0, 0);
      a = __builtin_amdgcn_mfma_f32_16x16x32_bf16(a1, bfr[nt * 3 + 1], a, 0, 0, 0);
      a = __builtin_amdgcn_mfma_f32_16x16x32_bf16(a2, bfr[nt * 3 + 2], a, 0, 0, 0);
#pragma unroll
      for (int j = 0; j < 4; ++j) {
        const float y = a[j] + bb[nt];
        ssum[nt] += y; ssq[nt] += y * y;
        y0[(size_t)(mt * 16 + khi * 4 + j) * 64 + nt * 16 + col] = f2bf(y);
      }
    }
  }
  flush_stats<64>(ssum, ssq, lane, stats_out);
}

// ===================== pipeline P2: finalize-inline + norm(yin) -> layer -> yout =====================
template <int DIN, int DOUT>
__global__ __launch_bounds__(256) void p2_kernel(
    const unsigned short* __restrict__ yin, const unsigned short* __restrict__ wp,
    const float* __restrict__ bias, const float* __restrict__ gprev,
    const float* __restrict__ bprev, const float* __restrict__ stats_prev, float n,
    unsigned short* __restrict__ yout, float* __restrict__ stats_out, int MT) {
  constexpr int KK = DIN / 32, NT = DOUT / 16;
  const int t = threadIdx.x, lane = t & 63;
  const int col = lane & 15, khi = lane >> 4;
  const int wid = rfl(t >> 6);
  const int w0 = blockIdx.x * 4 + wid;
  short8 bfr[NT * KK];
#pragma unroll
  for (int i = 0; i < NT * KK; ++i)
    bfr[i] = *reinterpret_cast<const short8*>(wp + ((size_t)i * 64 + lane) * 8);
  float bb[NT];
#pragma unroll
  for (int nt = 0; nt < NT; ++nt) bb[nt] = bias[nt * 16 + col];
  float ar[KK][8], cr[KK][8];
#pragma unroll
  for (int kk = 0; kk < KK; ++kk)
#pragma unroll
    for (int j = 0; j < 8; ++j) {
      const int ch = kk * 32 + khi * 8 + j;
      const float mu = stats_prev[ch] / n;
      const float var = stats_prev[DIN + ch] / n - mu * mu;
      const float a = gprev[ch] / sqrtf(var + EPS_);
      ar[kk][j] = a;
      cr[kk][j] = bprev[ch] - mu * a;
    }
  float ssum[NT], ssq[NT];
#pragma unroll
  for (int nt = 0; nt < NT; ++nt) { ssum[nt] = 0.f; ssq[nt] = 0.f; }
  for (int mt = w0; mt < MT; mt += 8192) {
    const size_t rb = (size_t)(mt * 16 + col) * DIN;
    short8 af[KK];
#pragma unroll
    for (int kk = 0; kk < KK; ++kk) {
      const short8 raw = *reinterpret_cast<const short8*>(yin + rb + kk * 32 + khi * 8);
#pragma unroll
      for (int j = 0; j < 8; ++j) {
        const float v = bf2f((unsigned short)raw[j]) * ar[kk][j] + cr[kk][j];
        af[kk][j] = (short)f2bf(fmaxf(v, 0.f));
      }
    }
#pragma unroll
    for (int nt = 0; nt < NT; ++nt) {
      f32x4 a = {0.f, 0.f, 0.f, 0.f};
#pragma unroll
      for (int kk = 0; kk < KK; ++kk)
        a = __builtin_amdgcn_mfma_f32_16x16x32_bf16(af[kk], bfr[nt * KK + kk], a, 0, 0, 0);
#pragma unroll
      for (int j = 0; j < 4; ++j) {
        const float y = a[j] + bb[nt];
        ssum[nt] += y; ssq[nt] += y * y;
        yout[(size_t)(mt * 16 + khi * 4 + j) * DOUT + nt * 16 + col] = f2bf(y);
      }
    }
  }
  flush_stats<DOUT>(ssum, ssq, lane, stats_out);
}

// ===================== pipeline P3: finalize-inline + norm(y1) -> layer2 -> stats + k-max ==========
template <int DIN, int K>
__global__ __launch_bounds__(256) void p3_kernel(
    const unsigned short* __restrict__ yin, const unsigned short* __restrict__ wp,
    const float* __restrict__ bias, const float* __restrict__ gprev,
    const float* __restrict__ bprev, const float* __restrict__ stats_prev, float n,
    float* __restrict__ maxtmp, float* __restrict__ stats_out) {
  constexpr int KK = DIN / 32, NT = 8;
  const int t = threadIdx.x, lane = t & 63;
  const int col = lane & 15, khi = lane >> 4;
  const int wid = rfl(t >> 6);
  const int c = blockIdx.x * 4 + wid;
  short8 bfr[NT * KK];
#pragma unroll
  for (int i = 0; i < NT * KK; ++i)
    bfr[i] = *reinterpret_cast<const short8*>(wp + ((size_t)i * 64 + lane) * 8);
  float bb[NT];
#pragma unroll
  for (int nt = 0; nt < NT; ++nt) bb[nt] = bias[nt * 16 + col];
  float ar[KK][8], cr[KK][8];
#pragma unroll
  for (int kk = 0; kk < KK; ++kk)
#pragma unroll
    for (int j = 0; j < 8; ++j) {
      const int ch = kk * 32 + khi * 8 + j;
      const float mu = stats_prev[ch] / n;
      const float var = stats_prev[DIN + ch] / n - mu * mu;
      const float a = gprev[ch] / sqrtf(var + EPS_);
      ar[kk][j] = a;
      cr[kk][j] = bprev[ch] - mu * a;
    }
  float ssum[NT], ssq[NT], mx[NT];
#pragma unroll
  for (int nt = 0; nt < NT; ++nt) { ssum[nt] = 0.f; ssq[nt] = 0.f; mx[nt] = -3.4e38f; }
#pragma unroll
  for (int m = 0; m < K / 16; ++m) {
    const size_t rb = (size_t)(c * K + m * 16 + col) * DIN;
    short8 af[KK];
#pragma unroll
    for (int kk = 0; kk < KK; ++kk) {
      const short8 raw = *reinterpret_cast<const short8*>(yin + rb + kk * 32 + khi * 8);
#pragma unroll
      for (int j = 0; j < 8; ++j) {
        const float v = bf2f((unsigned short)raw[j]) * ar[kk][j] + cr[kk][j];
        af[kk][j] = (short)f2bf(fmaxf(v, 0.f));
      }
    }
#pragma unroll
    for (int nt = 0; nt < NT; ++nt) {
      f32x4 a = {0.f, 0.f, 0.f, 0.f};
#pragma unroll
      for (int kk = 0; kk < KK; ++kk)
        a = __builtin_amdgcn_mfma_f32_16x16x32_bf16(af[kk], bfr[nt * KK + kk], a, 0, 0, 0);
#pragma unroll
      for (int j = 0; j < 4; ++j) {
        const float y = a[j] + bb[nt];
        ssum[nt] += y; ssq[nt] += y * y;
        mx[nt] = fmaxf(mx[nt], y);
      }
    }
  }
#pragma unroll
  for (int nt = 0; nt < NT; ++nt) {
    mx[nt] = fmaxf(mx[nt], __shfl_xor(mx[nt], 16));
    mx[nt] = fmaxf(mx[nt], __shfl_xor(mx[nt], 32));
  }
  if (lane < 16) {
#pragma unroll
    for (int nt = 0; nt < NT; ++nt) maxtmp[(size_t)c * 128 + nt * 16 + lane] = mx[nt];
  }
  flush_stats<128>(ssum, ssq, lane, stats_out);
}

// ===================== out: finalize-inline affine + transpose-write =====================
__global__ __launch_bounds__(256) void out_kernel(const float* __restrict__ maxtmp,
                                                  const float* __restrict__ stats2,
                                                  const float* __restrict__ g2,
                                                  const float* __restrict__ be2, float n,
                                                  float* __restrict__ outf, int coff) {
  const int i = blockIdx.x * 256 + threadIdx.x;
  if (i >= B_ * 128 * S_) return;
  const int s = i & 511;
  const int o = (i >> 9) & 127;
  const int b = i >> 16;
  const float mu = stats2[o] / n;
  const float var = stats2[128 + o] / n - mu * mu;
  const float a = g2[o] / sqrtf(var + EPS_);
  const float c = be2[o] - mu * a;
  const float v = maxtmp[((size_t)(b * S_ + s)) * 128 + o];
  outf[((size_t)b * 256 + coff + o) * S_ + s] = a * v + c;
}

// ===================== fallback path (round-2 stage_mfma) =====================
template <int K, bool FT>
DEV void gather_tile(unsigned short* sX, const float* __restrict__ xyz,
                     const float* __restrict__ feat, const unsigned short* __restrict__ featT,
                     const float* __restrict__ newxyz, const int* __restrict__ idx, int tile) {
  const int t = threadIdx.x, r = t & 63, c4 = t >> 6;
  const int rep = r / K, k = r % K;
  const int cs = tile * (64 / K) + rep, b = cs >> 9;
  const int pi = idx[(size_t)cs * K + k];
  unsigned short* dst = sX + r * 104;
  if (FT) {
    const unsigned short* src = featT + (((size_t)b * N_ + pi) << 6) + c4 * 16;
    *reinterpret_cast<short8*>(dst + c4 * 16)     = *reinterpret_cast<const short8*>(src);
    *reinterpret_cast<short8*>(dst + c4 * 16 + 8) = *reinterpret_cast<const short8*>(src + 8);
  } else {
#pragma unroll
    for (int j = 0; j < 16; ++j) {
      const int ch = c4 * 16 + j;
      dst[ch] = f2bf(feat[((size_t)b * CF_ + ch) * N_ + pi]);
    }
  }
  if (c4 == 0) {
    const float* P = xyz + ((size_t)b * N_ + pi) * 3;
    const float* C = newxyz + (size_t)cs * 3;
    dst[64] = f2bf(P[0] - C[0]);
    dst[65] = f2bf(P[1] - C[1]);
    dst[66] = f2bf(P[2] - C[2]);
  }
}

template <int NTILES, int KK>
DEV void layer_mfma(const unsigned short* sIn, int stride, const unsigned short* __restrict__ wp,
                    int lane, int wid, f32x4* acc) {
  short8 af[KK];
  const int arow = wid * 16 + (lane & 15);
  const int kof = (lane >> 4) * 8;
#pragma unroll
  for (int kk = 0; kk < KK; ++kk)
    af[kk] = *reinterpret_cast<const short8*>(sIn + arow * stride + kk * 32 + kof);
#pragma unroll
  for (int nt = 0; nt < NTILES; ++nt) {
    f32x4 a = {0.f, 0.f, 0.f, 0.f};
#pragma unroll
    for (int kk = 0; kk < KK; ++kk) {
      short8 bf = *reinterpret_cast<const short8*>(wp + ((size_t)(nt * KK + kk) * 64 + lane) * 8);
      a = __builtin_amdgcn_mfma_f32_16x16x32_bf16(af[kk], bf, a, 0, 0, 0);
    }
    acc[nt] = a;
  }
}

template <int K, int D0, int D1, int D2, int STAGE, bool FT>
__global__ __launch_bounds__(256) void stage_mfma(
    const float* __restrict__ xyz, const float* __restrict__ feat,
    const unsigned short* __restrict__ featT, const float* __restrict__ newxyz,
    const int* __restrict__ idx,
    const unsigned short* __restrict__ wp0, const unsigned short* __restrict__ wp1,
    const unsigned short* __restrict__ wp2,
    const float* __restrict__ b0, const float* __restrict__ b1, const float* __restrict__ b2,
    const float* __restrict__ ac0, const float* __restrict__ ac1,
    float* __restrict__ stats_out, float* __restrict__ maxtmp) {
  constexpr int CPB = 64 / K, NT = (B_ * S_) / CPB;
  constexpr int ST0 = 104, ST1 = 72, ST2 = (D1 == 96) ? 104 : 72;
  constexpr int KK0 = 3, KK1 = D0 / 32, KK2 = D1 / 32;
  constexpr int NT0 = D0 / 16, NT1 = D1 / 16, NT2 = D2 / 16;
  constexpr int DS = (STAGE == 1) ? D0 : (STAGE == 2) ? D1 : D2;
  constexpr int NTS = DS / 16;

  __shared__ unsigned short sX[64 * ST0];
  __shared__ unsigned short sY0[(STAGE >= 2) ? 64 * ST1 : 8];
  __shared__ unsigned short sY1[(STAGE == 3) ? 64 * ST2 : 8];
  __shared__ float smax[(STAGE == 3) ? 512 : 4];

  const int t = threadIdx.x, lane = t & 63;
  const int wid = rfl(t >> 6);
  const int col = lane & 15, khi = lane >> 4;

  for (int i = t; i < 64 * 37; i += 256) sX[(i / 37) * ST0 + 67 + (i % 37)] = 0;

  float b0r[NT0], a0r[NT0], c0r[NT0];
  float b1r[NT1], a1r[NT1], c1r[NT1];
  float b2r[NT2];
#pragma unroll
  for (int nt = 0; nt < NT0; ++nt) {
    b0r[nt] = b0[nt * 16 + col];
    if constexpr (STAGE >= 2) {
      a0r[nt] = ac0[nt * 16 + col];
      c0r[nt] = ac0[D0 + nt * 16 + col];
    }
  }
  if constexpr (STAGE >= 2) {
#pragma unroll
    for (int nt = 0; nt < NT1; ++nt) {
      b1r[nt] = b1[nt * 16 + col];
      if constexpr (STAGE == 3) {
        a1r[nt] = ac1[nt * 16 + col];
        c1r[nt] = ac1[D1 + nt * 16 + col];
      }
    }
  }
  if constexpr (STAGE == 3) {
#pragma unroll
    for (int nt = 0; nt < NT2; ++nt) b2r[nt] = b2[nt * 16 + col];
  }

  float ssum[NTS], ssq[NTS];
#pragma unroll
  for (int nt = 0; nt < NTS; ++nt) { ssum[nt] = 0.f; ssq[nt] = 0.f; }

  for (int tile = blockIdx.x; tile < NT; tile += gridDim.x) {
    __syncthreads();
    gather_tile<K, FT>(sX, xyz, feat, featT, newxyz, idx, tile);
    __syncthreads();

    f32x4 acc0[NT0];
    layer_mfma<NT0, KK0>(sX, ST0, wp0, lane, wid, acc0);
    if constexpr (STAGE == 1) {
#pragma unroll
      for (int nt = 0; nt < NT0; ++nt) {
        const float bb = b0r[nt];
#pragma unroll
        for (int j = 0; j < 4; ++j) {
          const float y = acc0[nt][j] + bb;
          ssum[nt] += y; ssq[nt] += y * y;
        }
      }
    } else {
#pragma unroll
      for (int nt = 0; nt < NT0; ++nt) {
#pragma unroll
        for (int j = 0; j < 4; ++j) {
          float y = (acc0[nt][j] + b0r[nt]) * a0r[nt] + c0r[nt];
          y = fmaxf(y, 0.f);
          sY0[(wid * 16 + khi * 4 + j) * ST1 + nt * 16 + col] = f2bf(y);
        }
      }
      __syncthreads();
      f32x4 acc1[NT1];
      layer_mfma<NT1, KK1>(sY0, ST1, wp1, lane, wid, acc1);
      if constexpr (STAGE == 2) {
#pragma unroll
        for (int nt = 0; nt < NT1; ++nt) {
          const float bb = b1r[nt];
#pragma unroll
          for (int j = 0; j < 4; ++j) {
            const float y = acc1[nt][j] + bb;
            ssum[nt] += y; ssq[nt] += y * y;
          }
        }
      } else {
#pragma unroll
        for (int nt = 0; nt < NT1; ++nt) {
#pragma unroll
          for (int j = 0; j < 4; ++j) {
            float y = (acc1[nt][j] + b1r[nt]) * a1r[nt] + c1r[nt];
            y = fmaxf(y, 0.f);
            sY1[(wid * 16 + khi * 4 + j) * ST2 + nt * 16 + col] = f2bf(y);
          }
        }
        __syncthreads();
        f32x4 acc2[NT2];
        layer_mfma<NT2, KK2>(sY1, ST2, wp2, lane, wid, acc2);
#pragma unroll
        for (int nt = 0; nt < NT2; ++nt) {
          const float bb = b2r[nt];
          const float y0 = acc2[nt][0] + bb, y1 = acc2[nt][1] + bb;
          const float y2 = acc2[nt][2] + bb, y3 = acc2[nt][3] + bb;
          ssum[nt] += (y0 + y1) + (y2 + y3);
          ssq[nt] += (y0 * y0 + y1 * y1) + (y2 * y2 + y3 * y3);
          float m = fmaxf(fmaxf(y0, y1), fmaxf(y2, y3));
          m = fmaxf(m, __shfl_xor(m, 16));
          m = fmaxf(m, __shfl_xor(m, 32));
          if (lane < 16) smax[wid * 128 + nt * 16 + lane] = m;
        }
        __syncthreads();
        if constexpr (K == 64) {
          if (t < 128) {
            const float m = fmaxf(fmaxf(smax[t], smax[128 + t]), fmaxf(smax[256 + t], smax[384 + t]));
            maxtmp[(size_t)tile * 128 + t] = m;
          }
        } else {
          const int ce = t >> 7, ch = t & 127;
          const float m = fmaxf(smax[ce * 256 + ch], smax[ce * 256 + 128 + ch]);
          maxtmp[((size_t)(tile * 2 + ce)) * 128 + ch] = m;
        }
      }
    }
  }
  flush_stats<DS>(ssum, ssq, lane, stats_out);
}

__global__ void finalize_kernel(const float* __restrict__ stats, const float* __restrict__ g,
                                const float* __restrict__ beta, float* __restrict__ ac,
                                float n, int cout) {
  const int t = threadIdx.x;
  if (t < cout) {
    const float mu = stats[t] / n;
    const float var = stats[cout + t] / n - mu * mu;
    const float a = g[t] / sqrtf(var + EPS_);
    ac[t] = a;
    ac[cout + t] = beta[t] - mu * a;
  }
}

}  // namespace

extern "C" void kernel_launch(void* const* d_in, const int* in_sizes, int n_in,
                              void* d_out, int out_size, void* d_ws, size_t ws_size,
                              hipStream_t stream) {
  const float* xyz  = (const float*)d_in[0];
  const float* feat = (const float*)d_in[1];
  const float* w00 = (const float*)d_in[2];  const float* b00 = (const float*)d_in[3];
  const float* g00 = (const float*)d_in[4];  const float* be00 = (const float*)d_in[5];
  const float* w01 = (const float*)d_in[6];  const float* b01 = (const float*)d_in[7];
  const float* g01 = (const float*)d_in[8];  const float* be01 = (const float*)d_in[9];
  const float* w02 = (const float*)d_in[10]; const float* b02 = (const float*)d_in[11];
  const float* g02 = (const float*)d_in[12]; const float* be02 = (const float*)d_in[13];
  const float* w10 = (const float*)d_in[14]; const float* b10 = (const float*)d_in[15];
  const float* g10 = (const float*)d_in[16]; const float* be10 = (const float*)d_in[17];
  const float* w11 = (const float*)d_in[18]; const float* b11 = (const float*)d_in[19];
  const float* g11 = (const float*)d_in[20]; const float* be11 = (const float*)d_in[21];
  const float* w12 = (const float*)d_in[22]; const float* b12 = (const float*)d_in[23];
  const float* g12 = (const float*)d_in[24]; const float* be12 = (const float*)d_in[25];

  float* ws = (float*)d_ws;
  int* idx0 = (int*)(ws + IDX0_OFF);
  int* idx1 = (int*)(ws + IDX1_OFF);
  float* stats = ws + STATS_OFF;
  float* ac = ws + AC_OFF;
  unsigned short* wp = (unsigned short*)(ws + WP_OFF);
  float* maxtmp = ws + MAXT_OFF;
  unsigned short* featT = (unsigned short*)(ws + FEATT_OFF);
  unsigned short* y0us = (unsigned short*)(ws + Y0_OFF);
  unsigned short* y1us = (unsigned short*)(ws + Y1_OFF);

  const bool usePipe = ws_size >= WS_NEED_PIPE;
  const bool useFT   = ws_size >= WS_NEED_FT;

  float* outF = (float*)d_out;          // new_xyz (B,S,3)
  float* outFeat = outF + B_ * S_ * 3;  // (B,256,S)

  prep_kernel<<<1024, 256, 0, stream>>>(feat, featT, useFT ? 1 : 0,
                                        w00, w01, w02, w10, w11, w12, wp, stats);
  fps_kernel<<<16, 256, 0, stream>>>(xyz, outF);
  ballq_both<<<4096, 256, 0, stream>>>(xyz, outF, idx0, idx1);

  const float n0 = (float)(B_ * S_ * 32);
  const float n1 = (float)(B_ * S_ * 64);

  if (usePipe) {
    // ---- scale 0: K=32, 67->64->64->128 ----
    p1_kernel<32><<<2048, 256, 0, stream>>>(xyz, featT, outF, idx0, wp + WP00, b00,
                                            y0us, stats + 0 * 256);
    p2_kernel<64, 64><<<2048, 256, 0, stream>>>(y0us, wp + WP01, b01, g00, be00,
                                                stats + 0 * 256, n0, y1us,
                                                stats + 1 * 256, 16384);
    p3_kernel<64, 32><<<2048, 256, 0, stream>>>(y1us, wp + WP02, b02, g01, be01,
                                                stats + 1 * 256, n0, maxtmp,
                                                stats + 2 * 256);
    out_kernel<<<4096, 256, 0, stream>>>(maxtmp, stats + 2 * 256, g02, be02, n0, outFeat, 0);

    // ---- scale 1: K=64, 67->64->96->128 ----
    p1_kernel<64><<<2048, 256, 0, stream>>>(xyz, featT, outF, idx1, wp + WP10, b10,
                                            y0us, stats + 3 * 256);
    p2_kernel<64, 96><<<2048, 256, 0, stream>>>(y0us, wp + WP11, b11, g10, be10,
                                                stats + 3 * 256, n1, y1us,
                                                stats + 4 * 256, 32768);
    p3_kernel<96, 64><<<2048, 256, 0, stream>>>(y1us, wp + WP12, b12, g11, be11,
                                                stats + 4 * 256, n1, maxtmp,
                                                stats + 5 * 256);
    out_kernel<<<4096, 256, 0, stream>>>(maxtmp, stats + 5 * 256, g12, be12, n1, outFeat, 128);
    return;
  }

#define LAUNCH_SCALE0(STG)                                                              \
  do {                                                                                  \
    if (useFT)                                                                          \
      stage_mfma<32, 64, 64, 128, STG, true><<<2048, 256, 0, stream>>>(                 \
          xyz, feat, featT, outF, idx0, wp + WP00, wp + WP01, wp + WP02, b00, b01, b02, \
          ac + 0 * 256, ac + 1 * 256, stats + (STG - 1) * 256, maxtmp);                 \
    else                                                                                \
      stage_mfma<32, 64, 64, 128, STG, false><<<2048, 256, 0, stream>>>(                \
          xyz, feat, featT, outF, idx0, wp + WP00, wp + WP01, wp + WP02, b00, b01, b02, \
          ac + 0 * 256, ac + 1 * 256, stats + (STG - 1) * 256, maxtmp);                 \
  } while (0)
#define LAUNCH_SCALE1(STG)                                                              \
  do {                                                                                  \
    if (useFT)                                                                          \
      stage_mfma<64, 64, 96, 128, STG, true><<<2048, 256, 0, stream>>>(                 \
          xyz, feat, featT, outF, idx1, wp + WP10, wp + WP11, wp + WP12, b10, b11, b12, \
          ac + 3 * 256, ac + 4 * 256, stats + (2 + STG) * 256, maxtmp);                 \
    else                                                                                \
      stage_mfma<64, 64, 96, 128, STG, false><<<2048, 256, 0, stream>>>(                \
          xyz, feat, featT, outF, idx1, wp + WP10, wp + WP11, wp + WP12, b10, b11, b12, \
          ac + 3 * 256, ac + 4 * 256, stats + (2 + STG) * 256, maxtmp);                 \
  } while (0)

  LAUNCH_SCALE0(1);
  finalize_kernel<<<1, 128, 0, stream>>>(stats + 0 * 256, g00, be00, ac + 0 * 256, n0, 64);
  LAUNCH_SCALE0(2);
  finalize_kernel<<<1, 128, 0, stream>>>(stats + 1 * 256, g01, be01, ac + 1 * 256, n0, 64);
  LAUNCH_SCALE0(3);
  out_kernel<<<4096, 256, 0, stream>>>(maxtmp, stats + 2 * 256, g02, be02, n0, outFeat, 0);

  LAUNCH_SCALE1(1);
  finalize_kernel<<<1, 128, 0, stream>>>(stats + 3 * 256, g10, be10, ac + 3 * 256, n1, 64);
  LAUNCH_SCALE1(2);
  finalize_kernel<<<1, 128, 0, stream>>>(stats + 4 * 256, g11, be11, ac + 4 * 256, n1, 96);
  LAUNCH_SCALE1(3);
  out_kernel<<<4096, 256, 0, stream>>>(maxtmp, stats + 5 * 256, g12, be12, n1, outFeat, 128);

#undef LAUNCH_SCALE0
#undef LAUNCH_SCALE1
}

// Round 6
// 723.137 us; speedup vs baseline: 3.3268x; 2.3845x over previous
//
#include <hip/hip_runtime.h>

#define DEV __device__ __forceinline__

namespace {

typedef __attribute__((ext_vector_type(8))) short short8;
typedef __attribute__((ext_vector_type(4))) float f32x4;

constexpr int B_ = 16, N_ = 4096, S_ = 512, CF_ = 64;
constexpr float EPS_ = 1e-5f;

// ---- ws layout (float units) ----
constexpr int IDX0_OFF  = 0;                     // B*S*32 ints
constexpr int IDX1_OFF  = 262144;                // B*S*64 ints
constexpr int STATS_OFF = IDX1_OFF + 524288;     // 6 stages * 32 copies * 256 f
constexpr int AC_OFF    = STATS_OFF + 49152;     // 6*256 f (fallback only)
constexpr int WP_OFF    = AC_OFF + 1536;         // 43008 ushorts = 21504 f
constexpr int MAXT_OFF  = WP_OFF + 21504;        // 8192*128 f
constexpr int FEATT_OFF = MAXT_OFF + 1048576;    // 4194304 ushorts = 2097152 f
constexpr int Y0_OFF    = FEATT_OFF + 2097152;   // 16777216 f
constexpr int Y1_OFF    = Y0_OFF + 16777216;     // 25165824 f
constexpr size_t WS_NEED_FT   = (size_t)Y0_OFF * 4;
constexpr size_t WS_NEED_PIPE = (size_t)(Y1_OFF + 25165824) * 4;

// packed-weight sub-offsets (ushort units)
constexpr int WP00 = 0,     WP01 = 6144,  WP02 = 10240;
constexpr int WP10 = 18432, WP11 = 24576, WP12 = 30720;

DEV int rfl(int x) { return __builtin_amdgcn_readfirstlane(x); }

DEV unsigned short f2bf(float x) {  // RNE float->bf16
  unsigned u = __float_as_uint(x);
  u += 0x7fff + ((u >> 16) & 1);
  return (unsigned short)(u >> 16);
}
DEV float bf2f(unsigned short u) { return __uint_as_float((unsigned)u << 16); }

// ===================== FPS: f32 butterfly + ballot argmax =====================
__global__ __launch_bounds__(256) void fps_kernel(const float* __restrict__ xyz,
                                                  float* __restrict__ newxyz) {
  __shared__ float px[N_], py[N_], pz[N_];
  __shared__ float swm[2][4];
  __shared__ int   swi[2][4];
  __shared__ int   seq[S_];
  const int b = blockIdx.x, t = threadIdx.x;
  const int lane = t & 63, wv = t >> 6;
  const float* xb = xyz + (size_t)b * N_ * 3;
  for (int i = t; i < N_; i += 256) {
    px[i] = xb[i * 3 + 0];
    py[i] = xb[i * 3 + 1];
    pz[i] = xb[i * 3 + 2];
  }
  __syncthreads();
  float X[16], Y[16], Z[16], D[16];
#pragma unroll
  for (int j = 0; j < 16; ++j) {
    X[j] = px[t * 16 + j];
    Y[j] = py[t * 16 + j];
    Z[j] = pz[t * 16 + j];
    D[j] = 1e10f;
  }
  float cx = px[0], cy = py[0], cz = pz[0];
  if (t == 0) seq[0] = 0;
  for (int it = 1; it < S_; ++it) {
    const int p = it & 1;
    float bv = -1.0f;
    int bi = 0x7fffffff;
#pragma unroll
    for (int j = 0; j < 16; ++j) {
      float d;
      {
#pragma clang fp contract(off)
        float dx = X[j] - cx, dy = Y[j] - cy, dz = Z[j] - cz;
        d = (dx * dx + dy * dy) + dz * dz;
      }
      const float dm = D[j] < d ? D[j] : d;
      D[j] = dm;
      if (dm > bv) { bv = dm; bi = t * 16 + j; }  // strict > keeps lowest index
    }
    // wave max (f32), then lowest tying lane (lane index monotone in candidate index)
    float mx = bv;
#pragma unroll
    for (int m = 1; m < 64; m <<= 1) mx = fmaxf(mx, __shfl_xor(mx, m));
    const unsigned long long tie = __ballot(bv == mx);
    const int srcLane = (int)__builtin_ctzll(tie);
    const int wbi = __shfl(bi, srcLane);
    if (lane == 0) { swm[p][wv] = mx; swi[p][wv] = wbi; }
    __syncthreads();
    float rv = swm[p][0];
    int   ri = swi[p][0];
#pragma unroll
    for (int r = 1; r < 4; ++r) {
      const float v = swm[p][r];
      const int   i = swi[p][r];
      if (v > rv || (v == rv && i < ri)) { rv = v; ri = i; }
    }
    cx = px[ri]; cy = py[ri]; cz = pz[ri];
    if (t == 0) seq[it] = ri;
  }
  __syncthreads();
  for (int i = t; i < S_; i += 256) {
    const int ri = seq[i];
    newxyz[(size_t)(b * S_ + i) * 3 + 0] = px[ri];
    newxyz[(size_t)(b * S_ + i) * 3 + 1] = py[ri];
    newxyz[(size_t)(b * S_ + i) * 3 + 2] = pz[ri];
  }
}

// ===================== Ball query (both scales in one launch) =====================
__global__ __launch_bounds__(256) void ballq_both(const float* __restrict__ xyz,
                                                  const float* __restrict__ newxyz,
                                                  int* __restrict__ idx0,
                                                  int* __restrict__ idx1) {
  __shared__ int sbuf[4][64];
  const int blk = blockIdx.x;
  const int scale = blk >> 11;
  const int cb = blk & 2047;
  const int NS = scale ? 64 : 32;
  const float r2 = scale ? 0.4f * 0.4f : 0.2f * 0.2f;
  int* __restrict__ idx = scale ? idx1 : idx0;
  const int wiv = threadIdx.x >> 6;
  const int lane = threadIdx.x & 63;
  const int cs = cb * 4 + wiv;
  const int b = cs >> 9;
  const float cx = newxyz[(size_t)cs * 3 + 0];
  const float cy = newxyz[(size_t)cs * 3 + 1];
  const float cz = newxyz[(size_t)cs * 3 + 2];
  const float* xb = xyz + (size_t)b * N_ * 3;
  int* my = sbuf[wiv];
  int cnt = 0;
  for (int base = 0; base < N_; base += 64) {
    if (cnt >= NS) break;
    const int i = base + lane;
    float d;
    {
#pragma clang fp contract(off)
      float dx = xb[i * 3 + 0] - cx, dy = xb[i * 3 + 1] - cy, dz = xb[i * 3 + 2] - cz;
      d = (dx * dx + dy * dy) + dz * dz;
    }
    const bool q = d < r2;
    const unsigned long long m = __ballot(q);
    if (q) {
      int pos = cnt + __popcll(m & ((1ull << lane) - 1ull));
      if (pos < NS) my[pos] = i;
    }
    cnt += __popcll(m);
  }
  __syncthreads();
  const int c = cnt < NS ? cnt : NS;
  const int first = my[0];
  for (int j = lane; j < NS; j += 64) idx[(size_t)cs * NS + j] = (j < c) ? my[j] : first;
}

// ===================== prep: stats zero + weight pack + feat transpose =====================
__global__ __launch_bounds__(256) void prep_kernel(
    const float* __restrict__ feat, unsigned short* __restrict__ featT, int doFT,
    const float* __restrict__ w00, const float* __restrict__ w01, const float* __restrict__ w02,
    const float* __restrict__ w10, const float* __restrict__ w11, const float* __restrict__ w12,
    unsigned short* __restrict__ wp, float* __restrict__ stats) {
  const int blk = blockIdx.x, t = threadIdx.x;
  if (blk < 24) {  // zero 6*32*256 floats across 24 blocks
    for (int i = blk * 2048 + t; i < (blk + 1) * 2048; i += 256) stats[i] = 0.f;
  }
  {  // weight pack (blocks 0..20)
    const int id = blk * 256 + t;
    const float* w = nullptr; int off = 0, KK = 0, CINW = 0, base = 0; bool perm = false;
    if (id < 768)       { w = w00; off = WP00; KK = 3; CINW = 67; perm = true;  base = 0; }
    else if (id < 1280) { w = w01; off = WP01; KK = 2; CINW = 64; perm = false; base = 768; }
    else if (id < 2304) { w = w02; off = WP02; KK = 2; CINW = 64; perm = false; base = 1280; }
    else if (id < 3072) { w = w10; off = WP10; KK = 3; CINW = 67; perm = true;  base = 2304; }
    else if (id < 3840) { w = w11; off = WP11; KK = 2; CINW = 64; perm = false; base = 3072; }
    else if (id < 5376) { w = w12; off = WP12; KK = 3; CINW = 96; perm = false; base = 3840; }
    if (w) {
      const int lid = id - base;
      const int lane = lid & 63, fr = lid >> 6;
      const int kk = fr % KK, nt = fr / KK;
      const int ccol = nt * 16 + (lane & 15);
      const int kbase = kk * 32 + (lane >> 4) * 8;
      unsigned short* dst = wp + off + (size_t)lid * 8;
#pragma unroll
      for (int j = 0; j < 8; ++j) {
        const int k = kbase + j;
        int cin;
        if (perm) cin = (k < 64) ? k + 3 : (k < 67 ? k - 64 : -1);
        else      cin = (k < CINW) ? k : -1;
        float f = (cin >= 0) ? w[ccol * CINW + cin] : 0.f;
        dst[j] = f2bf(f);
      }
    }
  }
  if (doFT) {  // feat transpose, 1024 blocks
    __shared__ unsigned short tile[64][65];
    const int b = blk >> 6, nc = blk & 63;
    const int n0 = nc * 64;
    for (int i = t; i < 64 * 64; i += 256) {
      int c = i >> 6, n = i & 63;
      tile[c][n] = f2bf(feat[((size_t)b * CF_ + c) * N_ + n0 + n]);
    }
    __syncthreads();
    for (int i = t; i < 64 * 64; i += 256) {
      int n = i >> 6, c = i & 63;
      featT[((size_t)b * N_ + n0 + n) * 64 + c] = tile[c][n];
    }
  }
}

// ===================== stats helpers (32-copy spread) =====================
template <int DS>
DEV void flush_stats(const float* ssum, const float* ssq, int lane, int slot,
                     float* __restrict__ sg) {
  constexpr int NTS = DS / 16;
  float* dst = sg + (size_t)slot * 256;
#pragma unroll
  for (int nt = 0; nt < NTS; ++nt) {
    float s = ssum[nt], q = ssq[nt];
    s += __shfl_xor(s, 16); q += __shfl_xor(q, 16);
    s += __shfl_xor(s, 32); q += __shfl_xor(q, 32);
    if (lane < 16) {
      atomicAdd(&dst[nt * 16 + lane], s);
      atomicAdd(&dst[DS + nt * 16 + lane], q);
    }
  }
}

// block-level reduce of the 32 copies into LDS (256 ch); includes barrier
DEV void reduce_stats_block(const float* __restrict__ sg, float* sstats, int t) {
  float s = 0.f;
#pragma unroll
  for (int c = 0; c < 32; ++c) s += sg[c * 256 + t];
  sstats[t] = s;
  __syncthreads();
}

// ===================== pipeline P1: gather + layer0 =====================
template <int K>
__global__ __launch_bounds__(256) void p1_kernel(
    const float* __restrict__ xyz, const unsigned short* __restrict__ featT,
    const float* __restrict__ newxyz, const int* __restrict__ idx,
    const unsigned short* __restrict__ wp0, const float* __restrict__ b0,
    unsigned short* __restrict__ y0, float* __restrict__ stats_out) {
  const int t = threadIdx.x, lane = t & 63;
  const int col = lane & 15, khi = lane >> 4;
  const int wid = rfl(t >> 6);
  constexpr int MT = (B_ * S_ * K) / 16;
  const int w0 = blockIdx.x * 4 + wid;
  short8 bfr[12];
#pragma unroll
  for (int i = 0; i < 12; ++i)
    bfr[i] = *reinterpret_cast<const short8*>(wp0 + ((size_t)i * 64 + lane) * 8);
  float bb[4];
#pragma unroll
  for (int nt = 0; nt < 4; ++nt) bb[nt] = b0[nt * 16 + col];
  float ssum[4] = {0.f, 0.f, 0.f, 0.f}, ssq[4] = {0.f, 0.f, 0.f, 0.f};
  for (int mt = w0; mt < MT; mt += 8192) {
    const int row = mt * 16 + col;
    const int cs = row / K;
    const int b = cs >> 9;
    const int pi = idx[row];
    const unsigned short* fr = featT + (((size_t)b * N_ + pi) << 6);
    const short8 a0 = *reinterpret_cast<const short8*>(fr + khi * 8);
    const short8 a1 = *reinterpret_cast<const short8*>(fr + 32 + khi * 8);
    short8 a2 = {0, 0, 0, 0, 0, 0, 0, 0};
    if (khi == 0) {
      const float* P = xyz + ((size_t)b * N_ + pi) * 3;
      const float* C = newxyz + (size_t)cs * 3;
      a2[0] = (short)f2bf(P[0] - C[0]);
      a2[1] = (short)f2bf(P[1] - C[1]);
      a2[2] = (short)f2bf(P[2] - C[2]);
    }
#pragma unroll
    for (int nt = 0; nt < 4; ++nt) {
      f32x4 a = {0.f, 0.f, 0.f, 0.f};
      a = __builtin_amdgcn_mfma_f32_16x16x32_bf16(a0, bfr[nt * 3 + 0], a, 0, 0, 0);
      a = __builtin_amdgcn_mfma_f32_16x16x32_bf16(a1, bfr[nt * 3 + 1], a, 0, 0, 0);
      a = __builtin_amdgcn_mfma_f32_16x16x32_bf16(a2, bfr[nt * 3 + 2], a, 0, 0, 0);
#pragma unroll
      for (int j = 0; j < 4; ++j) {
        const float y = a[j] + bb[nt];
        ssum[nt] += y; ssq[nt] += y * y;
        y0[(size_t)(mt * 16 + khi * 4 + j) * 64 + nt * 16 + col] = f2bf(y);
      }
    }
  }
  flush_stats<64>(ssum, ssq, lane, w0 & 31, stats_out);
}

// ===================== pipeline P2: stats-reduce + norm(yin) -> layer -> yout =====================
template <int DIN, int DOUT>
__global__ __launch_bounds__(256) void p2_kernel(
    const unsigned short* __restrict__ yin, const unsigned short* __restrict__ wp,
    const float* __restrict__ bias, const float* __restrict__ gprev,
    const float* __restrict__ bprev, const float* __restrict__ stats_prev, float n,
    unsigned short* __restrict__ yout, float* __restrict__ stats_out, int MT) {
  constexpr int KK = DIN / 32, NT = DOUT / 16;
  __shared__ float sstats[256];
  const int t = threadIdx.x, lane = t & 63;
  const int col = lane & 15, khi = lane >> 4;
  const int wid = rfl(t >> 6);
  const int w0 = blockIdx.x * 4 + wid;
  reduce_stats_block(stats_prev, sstats, t);
  short8 bfr[NT * KK];
#pragma unroll
  for (int i = 0; i < NT * KK; ++i)
    bfr[i] = *reinterpret_cast<const short8*>(wp + ((size_t)i * 64 + lane) * 8);
  float bb[NT];
#pragma unroll
  for (int nt = 0; nt < NT; ++nt) bb[nt] = bias[nt * 16 + col];
  float ar[KK][8], cr[KK][8];
#pragma unroll
  for (int kk = 0; kk < KK; ++kk)
#pragma unroll
    for (int j = 0; j < 8; ++j) {
      const int ch = kk * 32 + khi * 8 + j;
      const float mu = sstats[ch] / n;
      const float var = sstats[DIN + ch] / n - mu * mu;
      const float a = gprev[ch] / sqrtf(var + EPS_);
      ar[kk][j] = a;
      cr[kk][j] = bprev[ch] - mu * a;
    }
  float ssum[NT], ssq[NT];
#pragma unroll
  for (int nt = 0; nt < NT; ++nt) { ssum[nt] = 0.f; ssq[nt] = 0.f; }
  for (int mt = w0; mt < MT; mt += 8192) {
    const size_t rb = (size_t)(mt * 16 + col) * DIN;
    short8 af[KK];
#pragma unroll
    for (int kk = 0; kk < KK; ++kk) {
      const short8 raw = *reinterpret_cast<const short8*>(yin + rb + kk * 32 + khi * 8);
#pragma unroll
      for (int j = 0; j < 8; ++j) {
        const float v = bf2f((unsigned short)raw[j]) * ar[kk][j] + cr[kk][j];
        af[kk][j] = (short)f2bf(fmaxf(v, 0.f));
      }
    }
#pragma unroll
    for (int nt = 0; nt < NT; ++nt) {
      f32x4 a = {0.f, 0.f, 0.f, 0.f};
#pragma unroll
      for (int kk = 0; kk < KK; ++kk)
        a = __builtin_amdgcn_mfma_f32_16x16x32_bf16(af[kk], bfr[nt * KK + kk], a, 0, 0, 0);
#pragma unroll
      for (int j = 0; j < 4; ++j) {
        const float y = a[j] + bb[nt];
        ssum[nt] += y; ssq[nt] += y * y;
        yout[(size_t)(mt * 16 + khi * 4 + j) * DOUT + nt * 16 + col] = f2bf(y);
      }
    }
  }
  flush_stats<DOUT>(ssum, ssq, lane, w0 & 31, stats_out);
}

// ===================== pipeline P3: stats-reduce + norm(y1) -> layer2 -> stats + k-max =====
template <int DIN, int K>
__global__ __launch_bounds__(256) void p3_kernel(
    const unsigned short* __restrict__ yin, const unsigned short* __restrict__ wp,
    const float* __restrict__ bias, const float* __restrict__ gprev,
    const float* __restrict__ bprev, const float* __restrict__ stats_prev, float n,
    float* __restrict__ maxtmp, float* __restrict__ stats_out) {
  constexpr int KK = DIN / 32, NT = 8;
  __shared__ float sstats[256];
  const int t = threadIdx.x, lane = t & 63;
  const int col = lane & 15, khi = lane >> 4;
  const int wid = rfl(t >> 6);
  const int c = blockIdx.x * 4 + wid;
  reduce_stats_block(stats_prev, sstats, t);
  short8 bfr[NT * KK];
#pragma unroll
  for (int i = 0; i < NT * KK; ++i)
    bfr[i] = *reinterpret_cast<const short8*>(wp + ((size_t)i * 64 + lane) * 8);
  float bb[NT];
#pragma unroll
  for (int nt = 0; nt < NT; ++nt) bb[nt] = bias[nt * 16 + col];
  float ar[KK][8], cr[KK][8];
#pragma unroll
  for (int kk = 0; kk < KK; ++kk)
#pragma unroll
    for (int j = 0; j < 8; ++j) {
      const int ch = kk * 32 + khi * 8 + j;
      const float mu = sstats[ch] / n;
      const float var = sstats[DIN + ch] / n - mu * mu;
      const float a = gprev[ch] / sqrtf(var + EPS_);
      ar[kk][j] = a;
      cr[kk][j] = bprev[ch] - mu * a;
    }
  float ssum[NT], ssq[NT], mx[NT];
#pragma unroll
  for (int nt = 0; nt < NT; ++nt) { ssum[nt] = 0.f; ssq[nt] = 0.f; mx[nt] = -3.4e38f; }
#pragma unroll
  for (int m = 0; m < K / 16; ++m) {
    const size_t rb = (size_t)(c * K + m * 16 + col) * DIN;
    short8 af[KK];
#pragma unroll
    for (int kk = 0; kk < KK; ++kk) {
      const short8 raw = *reinterpret_cast<const short8*>(yin + rb + kk * 32 + khi * 8);
#pragma unroll
      for (int j = 0; j < 8; ++j) {
        const float v = bf2f((unsigned short)raw[j]) * ar[kk][j] + cr[kk][j];
        af[kk][j] = (short)f2bf(fmaxf(v, 0.f));
      }
    }
#pragma unroll
    for (int nt = 0; nt < NT; ++nt) {
      f32x4 a = {0.f, 0.f, 0.f, 0.f};
#pragma unroll
      for (int kk = 0; kk < KK; ++kk)
        a = __builtin_amdgcn_mfma_f32_16x16x32_bf16(af[kk], bfr[nt * KK + kk], a, 0, 0, 0);
#pragma unroll
      for (int j = 0; j < 4; ++j) {
        const float y = a[j] + bb[nt];
        ssum[nt] += y; ssq[nt] += y * y;
        mx[nt] = fmaxf(mx[nt], y);
      }
    }
  }
#pragma unroll
  for (int nt = 0; nt < NT; ++nt) {
    mx[nt] = fmaxf(mx[nt], __shfl_xor(mx[nt], 16));
    mx[nt] = fmaxf(mx[nt], __shfl_xor(mx[nt], 32));
  }
  if (lane < 16) {
#pragma unroll
    for (int nt = 0; nt < NT; ++nt) maxtmp[(size_t)c * 128 + nt * 16 + lane] = mx[nt];
  }
  flush_stats<128>(ssum, ssq, lane, c & 31, stats_out);
}

// ===================== out: stats-reduce + affine + transpose-write =====================
__global__ __launch_bounds__(256) void out_kernel(const float* __restrict__ maxtmp,
                                                  const float* __restrict__ stats2,
                                                  const float* __restrict__ g2,
                                                  const float* __restrict__ be2, float n,
                                                  float* __restrict__ outf, int coff) {
  __shared__ float sstats[256];
  const int t = threadIdx.x;
  reduce_stats_block(stats2, sstats, t);
  const int i = blockIdx.x * 256 + t;
  if (i >= B_ * 128 * S_) return;
  const int s = i & 511;
  const int o = (i >> 9) & 127;
  const int b = i >> 16;
  const float mu = sstats[o] / n;
  const float var = sstats[128 + o] / n - mu * mu;
  const float a = g2[o] / sqrtf(var + EPS_);
  const float c = be2[o] - mu * a;
  const float v = maxtmp[((size_t)(b * S_ + s)) * 128 + o];
  outf[((size_t)b * 256 + coff + o) * S_ + s] = a * v + c;
}

// ===================== fallback path (round-2 stage_mfma) =====================
template <int K, bool FT>
DEV void gather_tile(unsigned short* sX, const float* __restrict__ xyz,
                     const float* __restrict__ feat, const unsigned short* __restrict__ featT,
                     const float* __restrict__ newxyz, const int* __restrict__ idx, int tile) {
  const int t = threadIdx.x, r = t & 63, c4 = t >> 6;
  const int rep = r / K, k = r % K;
  const int cs = tile * (64 / K) + rep, b = cs >> 9;
  const int pi = idx[(size_t)cs * K + k];
  unsigned short* dst = sX + r * 104;
  if (FT) {
    const unsigned short* src = featT + (((size_t)b * N_ + pi) << 6) + c4 * 16;
    *reinterpret_cast<short8*>(dst + c4 * 16)     = *reinterpret_cast<const short8*>(src);
    *reinterpret_cast<short8*>(dst + c4 * 16 + 8) = *reinterpret_cast<const short8*>(src + 8);
  } else {
#pragma unroll
    for (int j = 0; j < 16; ++j) {
      const int ch = c4 * 16 + j;
      dst[ch] = f2bf(feat[((size_t)b * CF_ + ch) * N_ + pi]);
    }
  }
  if (c4 == 0) {
    const float* P = xyz + ((size_t)b * N_ + pi) * 3;
    const float* C = newxyz + (size_t)cs * 3;
    dst[64] = f2bf(P[0] - C[0]);
    dst[65] = f2bf(P[1] - C[1]);
    dst[66] = f2bf(P[2] - C[2]);
  }
}

template <int NTILES, int KK>
DEV void layer_mfma(const unsigned short* sIn, int stride, const unsigned short* __restrict__ wp,
                    int lane, int wid, f32x4* acc) {
  short8 af[KK];
  const int arow = wid * 16 + (lane & 15);
  const int kof = (lane >> 4) * 8;
#pragma unroll
  for (int kk = 0; kk < KK; ++kk)
    af[kk] = *reinterpret_cast<const short8*>(sIn + arow * stride + kk * 32 + kof);
#pragma unroll
  for (int nt = 0; nt < NTILES; ++nt) {
    f32x4 a = {0.f, 0.f, 0.f, 0.f};
#pragma unroll
    for (int kk = 0; kk < KK; ++kk) {
      short8 bf = *reinterpret_cast<const short8*>(wp + ((size_t)(nt * KK + kk) * 64 + lane) * 8);
      a = __builtin_amdgcn_mfma_f32_16x16x32_bf16(af[kk], bf, a, 0, 0, 0);
    }
    acc[nt] = a;
  }
}

template <int K, int D0, int D1, int D2, int STAGE, bool FT>
__global__ __launch_bounds__(256) void stage_mfma(
    const float* __restrict__ xyz, const float* __restrict__ feat,
    const unsigned short* __restrict__ featT, const float* __restrict__ newxyz,
    const int* __restrict__ idx,
    const unsigned short* __restrict__ wp0, const unsigned short* __restrict__ wp1,
    const unsigned short* __restrict__ wp2,
    const float* __restrict__ b0, const float* __restrict__ b1, const float* __restrict__ b2,
    const float* __restrict__ ac0, const float* __restrict__ ac1,
    float* __restrict__ stats_out, float* __restrict__ maxtmp) {
  constexpr int CPB = 64 / K, NT = (B_ * S_) / CPB;
  constexpr int ST0 = 104, ST1 = 72, ST2 = (D1 == 96) ? 104 : 72;
  constexpr int KK0 = 3, KK1 = D0 / 32, KK2 = D1 / 32;
  constexpr int NT0 = D0 / 16, NT1 = D1 / 16, NT2 = D2 / 16;
  constexpr int DS = (STAGE == 1) ? D0 : (STAGE == 2) ? D1 : D2;
  constexpr int NTS = DS / 16;

  __shared__ unsigned short sX[64 * ST0];
  __shared__ unsigned short sY0[(STAGE >= 2) ? 64 * ST1 : 8];
  __shared__ unsigned short sY1[(STAGE == 3) ? 64 * ST2 : 8];
  __shared__ float smax[(STAGE == 3) ? 512 : 4];

  const int t = threadIdx.x, lane = t & 63;
  const int wid = rfl(t >> 6);
  const int col = lane & 15, khi = lane >> 4;

  for (int i = t; i < 64 * 37; i += 256) sX[(i / 37) * ST0 + 67 + (i % 37)] = 0;

  float b0r[NT0], a0r[NT0], c0r[NT0];
  float b1r[NT1], a1r[NT1], c1r[NT1];
  float b2r[NT2];
#pragma unroll
  for (int nt = 0; nt < NT0; ++nt) {
    b0r[nt] = b0[nt * 16 + col];
    if constexpr (STAGE >= 2) {
      a0r[nt] = ac0[nt * 16 + col];
      c0r[nt] = ac0[D0 + nt * 16 + col];
    }
  }
  if constexpr (STAGE >= 2) {
#pragma unroll
    for (int nt = 0; nt < NT1; ++nt) {
      b1r[nt] = b1[nt * 16 + col];
      if constexpr (STAGE == 3) {
        a1r[nt] = ac1[nt * 16 + col];
        c1r[nt] = ac1[D1 + nt * 16 + col];
      }
    }
  }
  if constexpr (STAGE == 3) {
#pragma unroll
    for (int nt = 0; nt < NT2; ++nt) b2r[nt] = b2[nt * 16 + col];
  }

  float ssum[NTS], ssq[NTS];
#pragma unroll
  for (int nt = 0; nt < NTS; ++nt) { ssum[nt] = 0.f; ssq[nt] = 0.f; }

  for (int tile = blockIdx.x; tile < NT; tile += gridDim.x) {
    __syncthreads();
    gather_tile<K, FT>(sX, xyz, feat, featT, newxyz, idx, tile);
    __syncthreads();

    f32x4 acc0[NT0];
    layer_mfma<NT0, KK0>(sX, ST0, wp0, lane, wid, acc0);
    if constexpr (STAGE == 1) {
#pragma unroll
      for (int nt = 0; nt < NT0; ++nt) {
        const float bb = b0r[nt];
#pragma unroll
        for (int j = 0; j < 4; ++j) {
          const float y = acc0[nt][j] + bb;
          ssum[nt] += y; ssq[nt] += y * y;
        }
      }
    } else {
#pragma unroll
      for (int nt = 0; nt < NT0; ++nt) {
#pragma unroll
        for (int j = 0; j < 4; ++j) {
          float y = (acc0[nt][j] + b0r[nt]) * a0r[nt] + c0r[nt];
          y = fmaxf(y, 0.f);
          sY0[(wid * 16 + khi * 4 + j) * ST1 + nt * 16 + col] = f2bf(y);
        }
      }
      __syncthreads();
      f32x4 acc1[NT1];
      layer_mfma<NT1, KK1>(sY0, ST1, wp1, lane, wid, acc1);
      if constexpr (STAGE == 2) {
#pragma unroll
        for (int nt = 0; nt < NT1; ++nt) {
          const float bb = b1r[nt];
#pragma unroll
          for (int j = 0; j < 4; ++j) {
            const float y = acc1[nt][j] + bb;
            ssum[nt] += y; ssq[nt] += y * y;
          }
        }
      } else {
#pragma unroll
        for (int nt = 0; nt < NT1; ++nt) {
#pragma unroll
          for (int j = 0; j < 4; ++j) {
            float y = (acc1[nt][j] + b1r[nt]) * a1r[nt] + c1r[nt];
            y = fmaxf(y, 0.f);
            sY1[(wid * 16 + khi * 4 + j) * ST2 + nt * 16 + col] = f2bf(y);
          }
        }
        __syncthreads();
        f32x4 acc2[NT2];
        layer_mfma<NT2, KK2>(sY1, ST2, wp2, lane, wid, acc2);
#pragma unroll
        for (int nt = 0; nt < NT2; ++nt) {
          const float bb = b2r[nt];
          const float y0 = acc2[nt][0] + bb, y1 = acc2[nt][1] + bb;
          const float y2 = acc2[nt][2] + bb, y3 = acc2[nt][3] + bb;
          ssum[nt] += (y0 + y1) + (y2 + y3);
          ssq[nt] += (y0 * y0 + y1 * y1) + (y2 * y2 + y3 * y3);
          float m = fmaxf(fmaxf(y0, y1), fmaxf(y2, y3));
          m = fmaxf(m, __shfl_xor(m, 16));
          m = fmaxf(m, __shfl_xor(m, 32));
          if (lane < 16) smax[wid * 128 + nt * 16 + lane] = m;
        }
        __syncthreads();
        if constexpr (K == 64) {
          if (t < 128) {
            const float m = fmaxf(fmaxf(smax[t], smax[128 + t]), fmaxf(smax[256 + t], smax[384 + t]));
            maxtmp[(size_t)tile * 128 + t] = m;
          }
        } else {
          const int ce = t >> 7, ch = t & 127;
          const float m = fmaxf(smax[ce * 256 + ch], smax[ce * 256 + 128 + ch]);
          maxtmp[((size_t)(tile * 2 + ce)) * 128 + ch] = m;
        }
      }
    }
  }
  flush_stats<DS>(ssum, ssq, lane, (int)(blockIdx.x * 4 + wid) & 31, stats_out);
}

__global__ void finalize_kernel(const float* __restrict__ stats, const float* __restrict__ g,
                                const float* __restrict__ beta, float* __restrict__ ac,
                                float n, int cout) {
  const int t = threadIdx.x;
  if (t < cout) {
    float s = 0.f, q = 0.f;
#pragma unroll
    for (int c = 0; c < 32; ++c) {
      s += stats[c * 256 + t];
      q += stats[c * 256 + cout + t];
    }
    const float mu = s / n;
    const float var = q / n - mu * mu;
    const float a = g[t] / sqrtf(var + EPS_);
    ac[t] = a;
    ac[cout + t] = beta[t] - mu * a;
  }
}

}  // namespace

extern "C" void kernel_launch(void* const* d_in, const int* in_sizes, int n_in,
                              void* d_out, int out_size, void* d_ws, size_t ws_size,
                              hipStream_t stream) {
  const float* xyz  = (const float*)d_in[0];
  const float* feat = (const float*)d_in[1];
  const float* w00 = (const float*)d_in[2];  const float* b00 = (const float*)d_in[3];
  const float* g00 = (const float*)d_in[4];  const float* be00 = (const float*)d_in[5];
  const float* w01 = (const float*)d_in[6];  const float* b01 = (const float*)d_in[7];
  const float* g01 = (const float*)d_in[8];  const float* be01 = (const float*)d_in[9];
  const float* w02 = (const float*)d_in[10]; const float* b02 = (const float*)d_in[11];
  const float* g02 = (const float*)d_in[12]; const float* be02 = (const float*)d_in[13];
  const float* w10 = (const float*)d_in[14]; const float* b10 = (const float*)d_in[15];
  const float* g10 = (const float*)d_in[16]; const float* be10 = (const float*)d_in[17];
  const float* w11 = (const float*)d_in[18]; const float* b11 = (const float*)d_in[19];
  const float* g11 = (const float*)d_in[20]; const float* be11 = (const float*)d_in[21];
  const float* w12 = (const float*)d_in[22]; const float* b12 = (const float*)d_in[23];
  const float* g12 = (const float*)d_in[24]; const float* be12 = (const float*)d_in[25];

  float* ws = (float*)d_ws;
  int* idx0 = (int*)(ws + IDX0_OFF);
  int* idx1 = (int*)(ws + IDX1_OFF);
  float* stats = ws + STATS_OFF;     // 6 stages x 32 copies x 256
  float* ac = ws + AC_OFF;
  unsigned short* wp = (unsigned short*)(ws + WP_OFF);
  float* maxtmp = ws + MAXT_OFF;
  unsigned short* featT = (unsigned short*)(ws + FEATT_OFF);
  unsigned short* y0us = (unsigned short*)(ws + Y0_OFF);
  unsigned short* y1us = (unsigned short*)(ws + Y1_OFF);

  const bool usePipe = ws_size >= WS_NEED_PIPE;
  const bool useFT   = ws_size >= WS_NEED_FT;

  float* outF = (float*)d_out;          // new_xyz (B,S,3)
  float* outFeat = outF + B_ * S_ * 3;  // (B,256,S)

  prep_kernel<<<1024, 256, 0, stream>>>(feat, featT, useFT ? 1 : 0,
                                        w00, w01, w02, w10, w11, w12, wp, stats);
  fps_kernel<<<16, 256, 0, stream>>>(xyz, outF);
  ballq_both<<<4096, 256, 0, stream>>>(xyz, outF, idx0, idx1);

  const float n0 = (float)(B_ * S_ * 32);
  const float n1 = (float)(B_ * S_ * 64);
  float* st0 = stats + 0 * 8192;
  float* st1 = stats + 1 * 8192;
  float* st2 = stats + 2 * 8192;
  float* st3 = stats + 3 * 8192;
  float* st4 = stats + 4 * 8192;
  float* st5 = stats + 5 * 8192;

  if (usePipe) {
    // ---- scale 0: K=32, 67->64->64->128 ----
    p1_kernel<32><<<2048, 256, 0, stream>>>(xyz, featT, outF, idx0, wp + WP00, b00,
                                            y0us, st0);
    p2_kernel<64, 64><<<2048, 256, 0, stream>>>(y0us, wp + WP01, b01, g00, be00,
                                                st0, n0, y1us, st1, 16384);
    p3_kernel<64, 32><<<2048, 256, 0, stream>>>(y1us, wp + WP02, b02, g01, be01,
                                                st1, n0, maxtmp, st2);
    out_kernel<<<4096, 256, 0, stream>>>(maxtmp, st2, g02, be02, n0, outFeat, 0);

    // ---- scale 1: K=64, 67->64->96->128 ----
    p1_kernel<64><<<2048, 256, 0, stream>>>(xyz, featT, outF, idx1, wp + WP10, b10,
                                            y0us, st3);
    p2_kernel<64, 96><<<2048, 256, 0, stream>>>(y0us, wp + WP11, b11, g10, be10,
                                                st3, n1, y1us, st4, 32768);
    p3_kernel<96, 64><<<2048, 256, 0, stream>>>(y1us, wp + WP12, b12, g11, be11,
                                                st4, n1, maxtmp, st5);
    out_kernel<<<4096, 256, 0, stream>>>(maxtmp, st5, g12, be12, n1, outFeat, 128);
    return;
  }

#define LAUNCH_SCALE0(STG, ST)                                                          \
  do {                                                                                  \
    if (useFT)                                                                          \
      stage_mfma<32, 64, 64, 128, STG, true><<<2048, 256, 0, stream>>>(                 \
          xyz, feat, featT, outF, idx0, wp + WP00, wp + WP01, wp + WP02, b00, b01, b02, \
          ac + 0 * 256, ac + 1 * 256, ST, maxtmp);                                      \
    else                                                                                \
      stage_mfma<32, 64, 64, 128, STG, false><<<2048, 256, 0, stream>>>(                \
          xyz, feat, featT, outF, idx0, wp + WP00, wp + WP01, wp + WP02, b00, b01, b02, \
          ac + 0 * 256, ac + 1 * 256, ST, maxtmp);                                      \
  } while (0)
#define LAUNCH_SCALE1(STG, ST)                                                          \
  do {                                                                                  \
    if (useFT)                                                                          \
      stage_mfma<64, 64, 96, 128, STG, true><<<2048, 256, 0, stream>>>(                 \
          xyz, feat, featT, outF, idx1, wp + WP10, wp + WP11, wp + WP12, b10, b11, b12, \
          ac + 3 * 256, ac + 4 * 256, ST, maxtmp);                                      \
    else                                                                                \
      stage_mfma<64, 64, 96, 128, STG, false><<<2048, 256, 0, stream>>>(                \
          xyz, feat, featT, outF, idx1, wp + WP10, wp + WP11, wp + WP12, b10, b11, b12, \
          ac + 3 * 256, ac + 4 * 256, ST, maxtmp);                                      \
  } while (0)

  LAUNCH_SCALE0(1, st0);
  finalize_kernel<<<1, 128, 0, stream>>>(st0, g00, be00, ac + 0 * 256, n0, 64);
  LAUNCH_SCALE0(2, st1);
  finalize_kernel<<<1, 128, 0, stream>>>(st1, g01, be01, ac + 1 * 256, n0, 64);
  LAUNCH_SCALE0(3, st2);
  out_kernel<<<4096, 256, 0, stream>>>(maxtmp, st2, g02, be02, n0, outFeat, 0);

  LAUNCH_SCALE1(1, st3);
  finalize_kernel<<<1, 128, 0, stream>>>(st3, g10, be10, ac + 3 * 256, n1, 64);
  LAUNCH_SCALE1(2, st4);
  finalize_kernel<<<1, 128, 0, stream>>>(st4, g11, be11, ac + 4 * 256, n1, 96);
  LAUNCH_SCALE1(3, st5);
  out_kernel<<<4096, 256, 0, stream>>>(maxtmp, st5, g12, be12, n1, outFeat, 128);

#undef LAUNCH_SCALE0
#undef LAUNCH_SCALE1
}

// Round 7
// 546.964 us; speedup vs baseline: 4.3983x; 1.3221x over previous
//
#include <hip/hip_runtime.h>

#define DEV __device__ __forceinline__

namespace {

typedef __attribute__((ext_vector_type(8))) short short8;
typedef __attribute__((ext_vector_type(4))) float f32x4;
typedef __attribute__((ext_vector_type(2))) float f32x2;

constexpr int B_ = 16, N_ = 4096, S_ = 512, CF_ = 64;
constexpr float EPS_ = 1e-5f;

// ---- ws layout (float units) ----
constexpr int IDX0_OFF  = 0;                     // B*S*32 ints
constexpr int IDX1_OFF  = 262144;                // B*S*64 ints
constexpr int STATS_OFF = IDX1_OFF + 524288;     // 6 stages * 32 copies * 256 f
constexpr int AC_OFF    = STATS_OFF + 49152;     // 6*256 f (fallback only)
constexpr int WP_OFF    = AC_OFF + 1536;         // 43008 ushorts = 21504 f
constexpr int MAXT_OFF  = WP_OFF + 21504;        // 8192*128 f
constexpr int FEATT_OFF = MAXT_OFF + 1048576;    // 4194304 ushorts = 2097152 f
constexpr int Y0_OFF    = FEATT_OFF + 2097152;   // 16777216 f
constexpr int Y1_OFF    = Y0_OFF + 16777216;     // 25165824 f
constexpr size_t WS_NEED_FT   = (size_t)Y0_OFF * 4;
constexpr size_t WS_NEED_PIPE = (size_t)(Y1_OFF + 25165824) * 4;

// packed-weight sub-offsets (ushort units)
constexpr int WP00 = 0,     WP01 = 6144,  WP02 = 10240;
constexpr int WP10 = 18432, WP11 = 24576, WP12 = 30720;

DEV int rfl(int x) { return __builtin_amdgcn_readfirstlane(x); }

DEV unsigned short f2bf(float x) {  // RNE float->bf16
  unsigned u = __float_as_uint(x);
  u += 0x7fff + ((u >> 16) & 1);
  return (unsigned short)(u >> 16);
}
DEV float bf2f(unsigned short u) { return __uint_as_float((unsigned)u << 16); }

// 64-lane f32 max reduce via DPP; full-wave max valid in lane 63.
DEV float dpp_max64(float v) {
  int m;
  m = __builtin_amdgcn_update_dpp(__float_as_int(v), __float_as_int(v), 0xB1, 0xf, 0xf, false);
  v = fmaxf(v, __int_as_float(m));  // xor 1
  m = __builtin_amdgcn_update_dpp(__float_as_int(v), __float_as_int(v), 0x4E, 0xf, 0xf, false);
  v = fmaxf(v, __int_as_float(m));  // xor 2
  m = __builtin_amdgcn_update_dpp(__float_as_int(v), __float_as_int(v), 0x141, 0xf, 0xf, false);
  v = fmaxf(v, __int_as_float(m));  // half-row mirror (8)
  m = __builtin_amdgcn_update_dpp(__float_as_int(v), __float_as_int(v), 0x140, 0xf, 0xf, false);
  v = fmaxf(v, __int_as_float(m));  // row mirror (16)
  m = __builtin_amdgcn_update_dpp(__float_as_int(v), __float_as_int(v), 0x142, 0xa, 0xf, false);
  v = fmaxf(v, __int_as_float(m));  // row_bcast15 -> rows 1,3
  m = __builtin_amdgcn_update_dpp(__float_as_int(v), __float_as_int(v), 0x143, 0xc, 0xf, false);
  v = fmaxf(v, __int_as_float(m));  // row_bcast31 -> rows 2,3
  return v;
}

// ===================== FPS: DPP reduce + packed dists + u64 cross-wave keys =====================
__global__ __launch_bounds__(256) void fps_kernel(const float* __restrict__ xyz,
                                                  float* __restrict__ newxyz) {
  __shared__ float px[N_], py[N_], pz[N_];
  __shared__ unsigned long long swk[2][4];
  __shared__ int seq[S_];
  const int b = blockIdx.x, t = threadIdx.x;
  const int lane = t & 63, wv = t >> 6;
  const float* xb = xyz + (size_t)b * N_ * 3;
  for (int i = t; i < N_; i += 256) {
    px[i] = xb[i * 3 + 0];
    py[i] = xb[i * 3 + 1];
    pz[i] = xb[i * 3 + 2];
  }
  __syncthreads();
  f32x2 Xp[8], Yp[8], Zp[8], Dp[8];
#pragma unroll
  for (int jp = 0; jp < 8; ++jp) {
    Xp[jp] = *reinterpret_cast<const f32x2*>(&px[t * 16 + jp * 2]);
    Yp[jp] = *reinterpret_cast<const f32x2*>(&py[t * 16 + jp * 2]);
    Zp[jp] = *reinterpret_cast<const f32x2*>(&pz[t * 16 + jp * 2]);
    Dp[jp] = f32x2{1e10f, 1e10f};
  }
  float cx = px[0], cy = py[0], cz = pz[0];
  if (t == 0) seq[0] = 0;
  for (int it = 1; it < S_; ++it) {
    const int p = it & 1;
    f32x2 bvp = {-1.0f, -1.0f};
    {
#pragma clang fp contract(off)
      const f32x2 c2x = {cx, cx}, c2y = {cy, cy}, c2z = {cz, cz};
#pragma unroll
      for (int jp = 0; jp < 8; ++jp) {
        const f32x2 dx = Xp[jp] - c2x, dy = Yp[jp] - c2y, dz = Zp[jp] - c2z;
        const f32x2 d = (dx * dx + dy * dy) + dz * dz;
        Dp[jp] = __builtin_elementwise_min(Dp[jp], d);
        bvp = __builtin_elementwise_max(bvp, Dp[jp]);
      }
    }
    const float bv = fmaxf(bvp.x, bvp.y);
    int bj = 0;
#pragma unroll
    for (int j = 15; j >= 0; --j) {
      const float dj = Dp[j >> 1][j & 1];
      bj = (dj == bv) ? j : bj;  // lowest tying j survives
    }
    const int bi = t * 16 + bj;
    // wave reduce: DPP max -> lane63, readlane broadcast, ballot tie-break
    const float mxl = dpp_max64(bv);
    const float mx = __int_as_float(__builtin_amdgcn_readlane(__float_as_int(mxl), 63));
    const unsigned long long tie = __ballot(bv == mx);
    const int srcLane = (int)__builtin_ctzll(tie);
    const int wbi = __builtin_amdgcn_readlane(bi, srcLane);
    if (lane == 0)
      swk[p][wv] = ((unsigned long long)__float_as_uint(mx) << 32) | (unsigned)(~wbi);
    __syncthreads();
    const unsigned long long k0 = swk[p][0], k1 = swk[p][1];
    const unsigned long long k2 = swk[p][2], k3 = swk[p][3];
    const unsigned long long ka = k0 > k1 ? k0 : k1;
    const unsigned long long kb = k2 > k3 ? k2 : k3;
    const unsigned long long kw = ka > kb ? ka : kb;
    const int ri = (int)(~(unsigned)kw);
    cx = px[ri]; cy = py[ri]; cz = pz[ri];
    if (t == 0) seq[it] = ri;
  }
  __syncthreads();
  for (int i = t; i < S_; i += 256) {
    const int ri = seq[i];
    newxyz[(size_t)(b * S_ + i) * 3 + 0] = px[ri];
    newxyz[(size_t)(b * S_ + i) * 3 + 1] = py[ri];
    newxyz[(size_t)(b * S_ + i) * 3 + 2] = pz[ri];
  }
}

// ===================== Ball query (both scales in one launch) =====================
__global__ __launch_bounds__(256) void ballq_both(const float* __restrict__ xyz,
                                                  const float* __restrict__ newxyz,
                                                  int* __restrict__ idx0,
                                                  int* __restrict__ idx1) {
  __shared__ int sbuf[4][64];
  const int blk = blockIdx.x;
  const int scale = blk >> 11;
  const int cb = blk & 2047;
  const int NS = scale ? 64 : 32;
  const float r2 = scale ? 0.4f * 0.4f : 0.2f * 0.2f;
  int* __restrict__ idx = scale ? idx1 : idx0;
  const int wiv = threadIdx.x >> 6;
  const int lane = threadIdx.x & 63;
  const int cs = cb * 4 + wiv;
  const int b = cs >> 9;
  const float cx = newxyz[(size_t)cs * 3 + 0];
  const float cy = newxyz[(size_t)cs * 3 + 1];
  const float cz = newxyz[(size_t)cs * 3 + 2];
  const float* xb = xyz + (size_t)b * N_ * 3;
  int* my = sbuf[wiv];
  int cnt = 0;
  for (int base = 0; base < N_; base += 64) {
    if (cnt >= NS) break;
    const int i = base + lane;
    float d;
    {
#pragma clang fp contract(off)
      float dx = xb[i * 3 + 0] - cx, dy = xb[i * 3 + 1] - cy, dz = xb[i * 3 + 2] - cz;
      d = (dx * dx + dy * dy) + dz * dz;
    }
    const bool q = d < r2;
    const unsigned long long m = __ballot(q);
    if (q) {
      int pos = cnt + __popcll(m & ((1ull << lane) - 1ull));
      if (pos < NS) my[pos] = i;
    }
    cnt += __popcll(m);
  }
  __syncthreads();
  const int c = cnt < NS ? cnt : NS;
  const int first = my[0];
  for (int j = lane; j < NS; j += 64) idx[(size_t)cs * NS + j] = (j < c) ? my[j] : first;
}

// ===================== prep: stats zero + weight pack + feat transpose =====================
__global__ __launch_bounds__(256) void prep_kernel(
    const float* __restrict__ feat, unsigned short* __restrict__ featT, int doFT,
    const float* __restrict__ w00, const float* __restrict__ w01, const float* __restrict__ w02,
    const float* __restrict__ w10, const float* __restrict__ w11, const float* __restrict__ w12,
    unsigned short* __restrict__ wp, float* __restrict__ stats) {
  const int blk = blockIdx.x, t = threadIdx.x;
  if (blk < 24) {  // zero 6*32*256 floats across 24 blocks
    for (int i = blk * 2048 + t; i < (blk + 1) * 2048; i += 256) stats[i] = 0.f;
  }
  {  // weight pack (blocks 0..20)
    const int id = blk * 256 + t;
    const float* w = nullptr; int off = 0, KK = 0, CINW = 0, base = 0; bool perm = false;
    if (id < 768)       { w = w00; off = WP00; KK = 3; CINW = 67; perm = true;  base = 0; }
    else if (id < 1280) { w = w01; off = WP01; KK = 2; CINW = 64; perm = false; base = 768; }
    else if (id < 2304) { w = w02; off = WP02; KK = 2; CINW = 64; perm = false; base = 1280; }
    else if (id < 3072) { w = w10; off = WP10; KK = 3; CINW = 67; perm = true;  base = 2304; }
    else if (id < 3840) { w = w11; off = WP11; KK = 2; CINW = 64; perm = false; base = 3072; }
    else if (id < 5376) { w = w12; off = WP12; KK = 3; CINW = 96; perm = false; base = 3840; }
    if (w) {
      const int lid = id - base;
      const int lane = lid & 63, fr = lid >> 6;
      const int kk = fr % KK, nt = fr / KK;
      const int ccol = nt * 16 + (lane & 15);
      const int kbase = kk * 32 + (lane >> 4) * 8;
      unsigned short* dst = wp + off + (size_t)lid * 8;
#pragma unroll
      for (int j = 0; j < 8; ++j) {
        const int k = kbase + j;
        int cin;
        if (perm) cin = (k < 64) ? k + 3 : (k < 67 ? k - 64 : -1);
        else      cin = (k < CINW) ? k : -1;
        float f = (cin >= 0) ? w[ccol * CINW + cin] : 0.f;
        dst[j] = f2bf(f);
      }
    }
  }
  if (doFT) {  // feat transpose, 1024 blocks
    __shared__ unsigned short tile[64][65];
    const int b = blk >> 6, nc = blk & 63;
    const int n0 = nc * 64;
    for (int i = t; i < 64 * 64; i += 256) {
      int c = i >> 6, n = i & 63;
      tile[c][n] = f2bf(feat[((size_t)b * CF_ + c) * N_ + n0 + n]);
    }
    __syncthreads();
    for (int i = t; i < 64 * 64; i += 256) {
      int n = i >> 6, c = i & 63;
      featT[((size_t)b * N_ + n0 + n) * 64 + c] = tile[c][n];
    }
  }
}

// ===================== stats helpers (32-copy spread) =====================
template <int DS>
DEV void flush_stats(const float* ssum, const float* ssq, int lane, int slot,
                     float* __restrict__ sg) {
  constexpr int NTS = DS / 16;
  float* dst = sg + (size_t)slot * 256;
#pragma unroll
  for (int nt = 0; nt < NTS; ++nt) {
    float s = ssum[nt], q = ssq[nt];
    s += __shfl_xor(s, 16); q += __shfl_xor(q, 16);
    s += __shfl_xor(s, 32); q += __shfl_xor(q, 32);
    if (lane < 16) {
      atomicAdd(&dst[nt * 16 + lane], s);
      atomicAdd(&dst[DS + nt * 16 + lane], q);
    }
  }
}

// block-level reduce of the 32 copies into LDS (256 ch); includes barrier
DEV void reduce_stats_block(const float* __restrict__ sg, float* sstats, int t) {
  float s = 0.f;
#pragma unroll
  for (int c = 0; c < 32; ++c) s += sg[c * 256 + t];
  sstats[t] = s;
  __syncthreads();
}

// ===================== pipeline P1: gather + layer0 =====================
template <int K>
__global__ __launch_bounds__(256) void p1_kernel(
    const float* __restrict__ xyz, const unsigned short* __restrict__ featT,
    const float* __restrict__ newxyz, const int* __restrict__ idx,
    const unsigned short* __restrict__ wp0, const float* __restrict__ b0,
    unsigned short* __restrict__ y0, float* __restrict__ stats_out) {
  const int t = threadIdx.x, lane = t & 63;
  const int col = lane & 15, khi = lane >> 4;
  const int wid = rfl(t >> 6);
  constexpr int MT = (B_ * S_ * K) / 16;
  const int w0 = blockIdx.x * 4 + wid;
  short8 bfr[12];
#pragma unroll
  for (int i = 0; i < 12; ++i)
    bfr[i] = *reinterpret_cast<const short8*>(wp0 + ((size_t)i * 64 + lane) * 8);
  float bb[4];
#pragma unroll
  for (int nt = 0; nt < 4; ++nt) bb[nt] = b0[nt * 16 + col];
  float ssum[4] = {0.f, 0.f, 0.f, 0.f}, ssq[4] = {0.f, 0.f, 0.f, 0.f};
  for (int mt = w0; mt < MT; mt += 8192) {
    const int row = mt * 16 + col;
    const int cs = row / K;
    const int b = cs >> 9;
    const int pi = idx[row];
    const unsigned short* fr = featT + (((size_t)b * N_ + pi) << 6);
    const short8 a0 = *reinterpret_cast<const short8*>(fr + khi * 8);
    const short8 a1 = *reinterpret_cast<const short8*>(fr + 32 + khi * 8);
    short8 a2 = {0, 0, 0, 0, 0, 0, 0, 0};
    if (khi == 0) {
      const float* P = xyz + ((size_t)b * N_ + pi) * 3;
      const float* C = newxyz + (size_t)cs * 3;
      a2[0] = (short)f2bf(P[0] - C[0]);
      a2[1] = (short)f2bf(P[1] - C[1]);
      a2[2] = (short)f2bf(P[2] - C[2]);
    }
#pragma unroll
    for (int nt = 0; nt < 4; ++nt) {
      f32x4 a = {0.f, 0.f, 0.f, 0.f};
      a = __builtin_amdgcn_mfma_f32_16x16x32_bf16(a0, bfr[nt * 3 + 0], a, 0, 0, 0);
      a = __builtin_amdgcn_mfma_f32_16x16x32_bf16(a1, bfr[nt * 3 + 1], a, 0, 0, 0);
      a = __builtin_amdgcn_mfma_f32_16x16x32_bf16(a2, bfr[nt * 3 + 2], a, 0, 0, 0);
#pragma unroll
      for (int j = 0; j < 4; ++j) {
        const float y = a[j] + bb[nt];
        ssum[nt] += y; ssq[nt] += y * y;
        y0[(size_t)(mt * 16 + khi * 4 + j) * 64 + nt * 16 + col] = f2bf(y);
      }
    }
  }
  flush_stats<64>(ssum, ssq, lane, w0 & 31, stats_out);
}

// ===================== pipeline P2: stats-reduce + norm(yin) -> layer -> yout =====================
template <int DIN, int DOUT>
__global__ __launch_bounds__(256) void p2_kernel(
    const unsigned short* __restrict__ yin, const unsigned short* __restrict__ wp,
    const float* __restrict__ bias, const float* __restrict__ gprev,
    const float* __restrict__ bprev, const float* __restrict__ stats_prev, float n,
    unsigned short* __restrict__ yout, float* __restrict__ stats_out, int MT) {
  constexpr int KK = DIN / 32, NT = DOUT / 16;
  __shared__ float sstats[256];
  const int t = threadIdx.x, lane = t & 63;
  const int col = lane & 15, khi = lane >> 4;
  const int wid = rfl(t >> 6);
  const int w0 = blockIdx.x * 4 + wid;
  reduce_stats_block(stats_prev, sstats, t);
  short8 bfr[NT * KK];
#pragma unroll
  for (int i = 0; i < NT * KK; ++i)
    bfr[i] = *reinterpret_cast<const short8*>(wp + ((size_t)i * 64 + lane) * 8);
  float bb[NT];
#pragma unroll
  for (int nt = 0; nt < NT; ++nt) bb[nt] = bias[nt * 16 + col];
  float ar[KK][8], cr[KK][8];
#pragma unroll
  for (int kk = 0; kk < KK; ++kk)
#pragma unroll
    for (int j = 0; j < 8; ++j) {
      const int ch = kk * 32 + khi * 8 + j;
      const float mu = sstats[ch] / n;
      const float var = sstats[DIN + ch] / n - mu * mu;
      const float a = gprev[ch] / sqrtf(var + EPS_);
      ar[kk][j] = a;
      cr[kk][j] = bprev[ch] - mu * a;
    }
  float ssum[NT], ssq[NT];
#pragma unroll
  for (int nt = 0; nt < NT; ++nt) { ssum[nt] = 0.f; ssq[nt] = 0.f; }
  for (int mt = w0; mt < MT; mt += 8192) {
    const size_t rb = (size_t)(mt * 16 + col) * DIN;
    short8 af[KK];
#pragma unroll
    for (int kk = 0; kk < KK; ++kk) {
      const short8 raw = *reinterpret_cast<const short8*>(yin + rb + kk * 32 + khi * 8);
#pragma unroll
      for (int j = 0; j < 8; ++j) {
        const float v = bf2f((unsigned short)raw[j]) * ar[kk][j] + cr[kk][j];
        af[kk][j] = (short)f2bf(fmaxf(v, 0.f));
      }
    }
#pragma unroll
    for (int nt = 0; nt < NT; ++nt) {
      f32x4 a = {0.f, 0.f, 0.f, 0.f};
#pragma unroll
      for (int kk = 0; kk < KK; ++kk)
        a = __builtin_amdgcn_mfma_f32_16x16x32_bf16(af[kk], bfr[nt * KK + kk], a, 0, 0, 0);
#pragma unroll
      for (int j = 0; j < 4; ++j) {
        const float y = a[j] + bb[nt];
        ssum[nt] += y; ssq[nt] += y * y;
        yout[(size_t)(mt * 16 + khi * 4 + j) * DOUT + nt * 16 + col] = f2bf(y);
      }
    }
  }
  flush_stats<DOUT>(ssum, ssq, lane, w0 & 31, stats_out);
}

// ===================== pipeline P3: stats-reduce + norm(y1) -> layer2 -> stats + k-max =====
template <int DIN, int K>
__global__ __launch_bounds__(256) void p3_kernel(
    const unsigned short* __restrict__ yin, const unsigned short* __restrict__ wp,
    const float* __restrict__ bias, const float* __restrict__ gprev,
    const float* __restrict__ bprev, const float* __restrict__ stats_prev, float n,
    float* __restrict__ maxtmp, float* __restrict__ stats_out) {
  constexpr int KK = DIN / 32, NT = 8;
  __shared__ float sstats[256];
  const int t = threadIdx.x, lane = t & 63;
  const int col = lane & 15, khi = lane >> 4;
  const int wid = rfl(t >> 6);
  const int c = blockIdx.x * 4 + wid;
  reduce_stats_block(stats_prev, sstats, t);
  short8 bfr[NT * KK];
#pragma unroll
  for (int i = 0; i < NT * KK; ++i)
    bfr[i] = *reinterpret_cast<const short8*>(wp + ((size_t)i * 64 + lane) * 8);
  float bb[NT];
#pragma unroll
  for (int nt = 0; nt < NT; ++nt) bb[nt] = bias[nt * 16 + col];
  float ar[KK][8], cr[KK][8];
#pragma unroll
  for (int kk = 0; kk < KK; ++kk)
#pragma unroll
    for (int j = 0; j < 8; ++j) {
      const int ch = kk * 32 + khi * 8 + j;
      const float mu = sstats[ch] / n;
      const float var = sstats[DIN + ch] / n - mu * mu;
      const float a = gprev[ch] / sqrtf(var + EPS_);
      ar[kk][j] = a;
      cr[kk][j] = bprev[ch] - mu * a;
    }
  float ssum[NT], ssq[NT], mx[NT];
#pragma unroll
  for (int nt = 0; nt < NT; ++nt) { ssum[nt] = 0.f; ssq[nt] = 0.f; mx[nt] = -3.4e38f; }
#pragma unroll
  for (int m = 0; m < K / 16; ++m) {
    const size_t rb = (size_t)(c * K + m * 16 + col) * DIN;
    short8 af[KK];
#pragma unroll
    for (int kk = 0; kk < KK; ++kk) {
      const short8 raw = *reinterpret_cast<const short8*>(yin + rb + kk * 32 + khi * 8);
#pragma unroll
      for (int j = 0; j < 8; ++j) {
        const float v = bf2f((unsigned short)raw[j]) * ar[kk][j] + cr[kk][j];
        af[kk][j] = (short)f2bf(fmaxf(v, 0.f));
      }
    }
#pragma unroll
    for (int nt = 0; nt < NT; ++nt) {
      f32x4 a = {0.f, 0.f, 0.f, 0.f};
#pragma unroll
      for (int kk = 0; kk < KK; ++kk)
        a = __builtin_amdgcn_mfma_f32_16x16x32_bf16(af[kk], bfr[nt * KK + kk], a, 0, 0, 0);
#pragma unroll
      for (int j = 0; j < 4; ++j) {
        const float y = a[j] + bb[nt];
        ssum[nt] += y; ssq[nt] += y * y;
        mx[nt] = fmaxf(mx[nt], y);
      }
    }
  }
#pragma unroll
  for (int nt = 0; nt < NT; ++nt) {
    mx[nt] = fmaxf(mx[nt], __shfl_xor(mx[nt], 16));
    mx[nt] = fmaxf(mx[nt], __shfl_xor(mx[nt], 32));
  }
  if (lane < 16) {
#pragma unroll
    for (int nt = 0; nt < NT; ++nt) maxtmp[(size_t)c * 128 + nt * 16 + lane] = mx[nt];
  }
  flush_stats<128>(ssum, ssq, lane, c & 31, stats_out);
}

// ===================== out: stats-reduce + affine + transpose-write =====================
__global__ __launch_bounds__(256) void out_kernel(const float* __restrict__ maxtmp,
                                                  const float* __restrict__ stats2,
                                                  const float* __restrict__ g2,
                                                  const float* __restrict__ be2, float n,
                                                  float* __restrict__ outf, int coff) {
  __shared__ float sstats[256];
  const int t = threadIdx.x;
  reduce_stats_block(stats2, sstats, t);
  const int i = blockIdx.x * 256 + t;
  if (i >= B_ * 128 * S_) return;
  const int s = i & 511;
  const int o = (i >> 9) & 127;
  const int b = i >> 16;
  const float mu = sstats[o] / n;
  const float var = sstats[128 + o] / n - mu * mu;
  const float a = g2[o] / sqrtf(var + EPS_);
  const float c = be2[o] - mu * a;
  const float v = maxtmp[((size_t)(b * S_ + s)) * 128 + o];
  outf[((size_t)b * 256 + coff + o) * S_ + s] = a * v + c;
}

// ===================== fallback path (round-2 stage_mfma) =====================
template <int K, bool FT>
DEV void gather_tile(unsigned short* sX, const float* __restrict__ xyz,
                     const float* __restrict__ feat, const unsigned short* __restrict__ featT,
                     const float* __restrict__ newxyz, const int* __restrict__ idx, int tile) {
  const int t = threadIdx.x, r = t & 63, c4 = t >> 6;
  const int rep = r / K, k = r % K;
  const int cs = tile * (64 / K) + rep, b = cs >> 9;
  const int pi = idx[(size_t)cs * K + k];
  unsigned short* dst = sX + r * 104;
  if (FT) {
    const unsigned short* src = featT + (((size_t)b * N_ + pi) << 6) + c4 * 16;
    *reinterpret_cast<short8*>(dst + c4 * 16)     = *reinterpret_cast<const short8*>(src);
    *reinterpret_cast<short8*>(dst + c4 * 16 + 8) = *reinterpret_cast<const short8*>(src + 8);
  } else {
#pragma unroll
    for (int j = 0; j < 16; ++j) {
      const int ch = c4 * 16 + j;
      dst[ch] = f2bf(feat[((size_t)b * CF_ + ch) * N_ + pi]);
    }
  }
  if (c4 == 0) {
    const float* P = xyz + ((size_t)b * N_ + pi) * 3;
    const float* C = newxyz + (size_t)cs * 3;
    dst[64] = f2bf(P[0] - C[0]);
    dst[65] = f2bf(P[1] - C[1]);
    dst[66] = f2bf(P[2] - C[2]);
  }
}

template <int NTILES, int KK>
DEV void layer_mfma(const unsigned short* sIn, int stride, const unsigned short* __restrict__ wp,
                    int lane, int wid, f32x4* acc) {
  short8 af[KK];
  const int arow = wid * 16 + (lane & 15);
  const int kof = (lane >> 4) * 8;
#pragma unroll
  for (int kk = 0; kk < KK; ++kk)
    af[kk] = *reinterpret_cast<const short8*>(sIn + arow * stride + kk * 32 + kof);
#pragma unroll
  for (int nt = 0; nt < NTILES; ++nt) {
    f32x4 a = {0.f, 0.f, 0.f, 0.f};
#pragma unroll
    for (int kk = 0; kk < KK; ++kk) {
      short8 bf = *reinterpret_cast<const short8*>(wp + ((size_t)(nt * KK + kk) * 64 + lane) * 8);
      a = __builtin_amdgcn_mfma_f32_16x16x32_bf16(af[kk], bf, a, 0, 0, 0);
    }
    acc[nt] = a;
  }
}

template <int K, int D0, int D1, int D2, int STAGE, bool FT>
__global__ __launch_bounds__(256) void stage_mfma(
    const float* __restrict__ xyz, const float* __restrict__ feat,
    const unsigned short* __restrict__ featT, const float* __restrict__ newxyz,
    const int* __restrict__ idx,
    const unsigned short* __restrict__ wp0, const unsigned short* __restrict__ wp1,
    const unsigned short* __restrict__ wp2,
    const float* __restrict__ b0, const float* __restrict__ b1, const float* __restrict__ b2,
    const float* __restrict__ ac0, const float* __restrict__ ac1,
    float* __restrict__ stats_out, float* __restrict__ maxtmp) {
  constexpr int CPB = 64 / K, NT = (B_ * S_) / CPB;
  constexpr int ST0 = 104, ST1 = 72, ST2 = (D1 == 96) ? 104 : 72;
  constexpr int KK0 = 3, KK1 = D0 / 32, KK2 = D1 / 32;
  constexpr int NT0 = D0 / 16, NT1 = D1 / 16, NT2 = D2 / 16;
  constexpr int DS = (STAGE == 1) ? D0 : (STAGE == 2) ? D1 : D2;
  constexpr int NTS = DS / 16;

  __shared__ unsigned short sX[64 * ST0];
  __shared__ unsigned short sY0[(STAGE >= 2) ? 64 * ST1 : 8];
  __shared__ unsigned short sY1[(STAGE == 3) ? 64 * ST2 : 8];
  __shared__ float smax[(STAGE == 3) ? 512 : 4];

  const int t = threadIdx.x, lane = t & 63;
  const int wid = rfl(t >> 6);
  const int col = lane & 15, khi = lane >> 4;

  for (int i = t; i < 64 * 37; i += 256) sX[(i / 37) * ST0 + 67 + (i % 37)] = 0;

  float b0r[NT0], a0r[NT0], c0r[NT0];
  float b1r[NT1], a1r[NT1], c1r[NT1];
  float b2r[NT2];
#pragma unroll
  for (int nt = 0; nt < NT0; ++nt) {
    b0r[nt] = b0[nt * 16 + col];
    if constexpr (STAGE >= 2) {
      a0r[nt] = ac0[nt * 16 + col];
      c0r[nt] = ac0[D0 + nt * 16 + col];
    }
  }
  if constexpr (STAGE >= 2) {
#pragma unroll
    for (int nt = 0; nt < NT1; ++nt) {
      b1r[nt] = b1[nt * 16 + col];
      if constexpr (STAGE == 3) {
        a1r[nt] = ac1[nt * 16 + col];
        c1r[nt] = ac1[D1 + nt * 16 + col];
      }
    }
  }
  if constexpr (STAGE == 3) {
#pragma unroll
    for (int nt = 0; nt < NT2; ++nt) b2r[nt] = b2[nt * 16 + col];
  }

  float ssum[NTS], ssq[NTS];
#pragma unroll
  for (int nt = 0; nt < NTS; ++nt) { ssum[nt] = 0.f; ssq[nt] = 0.f; }

  for (int tile = blockIdx.x; tile < NT; tile += gridDim.x) {
    __syncthreads();
    gather_tile<K, FT>(sX, xyz, feat, featT, newxyz, idx, tile);
    __syncthreads();

    f32x4 acc0[NT0];
    layer_mfma<NT0, KK0>(sX, ST0, wp0, lane, wid, acc0);
    if constexpr (STAGE == 1) {
#pragma unroll
      for (int nt = 0; nt < NT0; ++nt) {
        const float bb = b0r[nt];
#pragma unroll
        for (int j = 0; j < 4; ++j) {
          const float y = acc0[nt][j] + bb;
          ssum[nt] += y; ssq[nt] += y * y;
        }
      }
    } else {
#pragma unroll
      for (int nt = 0; nt < NT0; ++nt) {
#pragma unroll
        for (int j = 0; j < 4; ++j) {
          float y = (acc0[nt][j] + b0r[nt]) * a0r[nt] + c0r[nt];
          y = fmaxf(y, 0.f);
          sY0[(wid * 16 + khi * 4 + j) * ST1 + nt * 16 + col] = f2bf(y);
        }
      }
      __syncthreads();
      f32x4 acc1[NT1];
      layer_mfma<NT1, KK1>(sY0, ST1, wp1, lane, wid, acc1);
      if constexpr (STAGE == 2) {
#pragma unroll
        for (int nt = 0; nt < NT1; ++nt) {
          const float bb = b1r[nt];
#pragma unroll
          for (int j = 0; j < 4; ++j) {
            const float y = acc1[nt][j] + bb;
            ssum[nt] += y; ssq[nt] += y * y;
          }
        }
      } else {
#pragma unroll
        for (int nt = 0; nt < NT1; ++nt) {
#pragma unroll
          for (int j = 0; j < 4; ++j) {
            float y = (acc1[nt][j] + b1r[nt]) * a1r[nt] + c1r[nt];
            y = fmaxf(y, 0.f);
            sY1[(wid * 16 + khi * 4 + j) * ST2 + nt * 16 + col] = f2bf(y);
          }
        }
        __syncthreads();
        f32x4 acc2[NT2];
        layer_mfma<NT2, KK2>(sY1, ST2, wp2, lane, wid, acc2);
#pragma unroll
        for (int nt = 0; nt < NT2; ++nt) {
          const float bb = b2r[nt];
          const float y0 = acc2[nt][0] + bb, y1 = acc2[nt][1] + bb;
          const float y2 = acc2[nt][2] + bb, y3 = acc2[nt][3] + bb;
          ssum[nt] += (y0 + y1) + (y2 + y3);
          ssq[nt] += (y0 * y0 + y1 * y1) + (y2 * y2 + y3 * y3);
          float m = fmaxf(fmaxf(y0, y1), fmaxf(y2, y3));
          m = fmaxf(m, __shfl_xor(m, 16));
          m = fmaxf(m, __shfl_xor(m, 32));
          if (lane < 16) smax[wid * 128 + nt * 16 + lane] = m;
        }
        __syncthreads();
        if constexpr (K == 64) {
          if (t < 128) {
            const float m = fmaxf(fmaxf(smax[t], smax[128 + t]), fmaxf(smax[256 + t], smax[384 + t]));
            maxtmp[(size_t)tile * 128 + t] = m;
          }
        } else {
          const int ce = t >> 7, ch = t & 127;
          const float m = fmaxf(smax[ce * 256 + ch], smax[ce * 256 + 128 + ch]);
          maxtmp[((size_t)(tile * 2 + ce)) * 128 + ch] = m;
        }
      }
    }
  }
  flush_stats<DS>(ssum, ssq, lane, (int)(blockIdx.x * 4 + wid) & 31, stats_out);
}

__global__ void finalize_kernel(const float* __restrict__ stats, const float* __restrict__ g,
                                const float* __restrict__ beta, float* __restrict__ ac,
                                float n, int cout) {
  const int t = threadIdx.x;
  if (t < cout) {
    float s = 0.f, q = 0.f;
#pragma unroll
    for (int c = 0; c < 32; ++c) {
      s += stats[c * 256 + t];
      q += stats[c * 256 + cout + t];
    }
    const float mu = s / n;
    const float var = q / n - mu * mu;
    const float a = g[t] / sqrtf(var + EPS_);
    ac[t] = a;
    ac[cout + t] = beta[t] - mu * a;
  }
}

}  // namespace

extern "C" void kernel_launch(void* const* d_in, const int* in_sizes, int n_in,
                              void* d_out, int out_size, void* d_ws, size_t ws_size,
                              hipStream_t stream) {
  const float* xyz  = (const float*)d_in[0];
  const float* feat = (const float*)d_in[1];
  const float* w00 = (const float*)d_in[2];  const float* b00 = (const float*)d_in[3];
  const float* g00 = (const float*)d_in[4];  const float* be00 = (const float*)d_in[5];
  const float* w01 = (const float*)d_in[6];  const float* b01 = (const float*)d_in[7];
  const float* g01 = (const float*)d_in[8];  const float* be01 = (const float*)d_in[9];
  const float* w02 = (const float*)d_in[10]; const float* b02 = (const float*)d_in[11];
  const float* g02 = (const float*)d_in[12]; const float* be02 = (const float*)d_in[13];
  const float* w10 = (const float*)d_in[14]; const float* b10 = (const float*)d_in[15];
  const float* g10 = (const float*)d_in[16]; const float* be10 = (const float*)d_in[17];
  const float* w11 = (const float*)d_in[18]; const float* b11 = (const float*)d_in[19];
  const float* g11 = (const float*)d_in[20]; const float* be11 = (const float*)d_in[21];
  const float* w12 = (const float*)d_in[22]; const float* b12 = (const float*)d_in[23];
  const float* g12 = (const float*)d_in[24]; const float* be12 = (const float*)d_in[25];

  float* ws = (float*)d_ws;
  int* idx0 = (int*)(ws + IDX0_OFF);
  int* idx1 = (int*)(ws + IDX1_OFF);
  float* stats = ws + STATS_OFF;     // 6 stages x 32 copies x 256
  float* ac = ws + AC_OFF;
  unsigned short* wp = (unsigned short*)(ws + WP_OFF);
  float* maxtmp = ws + MAXT_OFF;
  unsigned short* featT = (unsigned short*)(ws + FEATT_OFF);
  unsigned short* y0us = (unsigned short*)(ws + Y0_OFF);
  unsigned short* y1us = (unsigned short*)(ws + Y1_OFF);

  const bool usePipe = ws_size >= WS_NEED_PIPE;
  const bool useFT   = ws_size >= WS_NEED_FT;

  float* outF = (float*)d_out;          // new_xyz (B,S,3)
  float* outFeat = outF + B_ * S_ * 3;  // (B,256,S)

  prep_kernel<<<1024, 256, 0, stream>>>(feat, featT, useFT ? 1 : 0,
                                        w00, w01, w02, w10, w11, w12, wp, stats);
  fps_kernel<<<16, 256, 0, stream>>>(xyz, outF);
  ballq_both<<<4096, 256, 0, stream>>>(xyz, outF, idx0, idx1);

  const float n0 = (float)(B_ * S_ * 32);
  const float n1 = (float)(B_ * S_ * 64);
  float* st0 = stats + 0 * 8192;
  float* st1 = stats + 1 * 8192;
  float* st2 = stats + 2 * 8192;
  float* st3 = stats + 3 * 8192;
  float* st4 = stats + 4 * 8192;
  float* st5 = stats + 5 * 8192;

  if (usePipe) {
    // ---- scale 0: K=32, 67->64->64->128 ----
    p1_kernel<32><<<2048, 256, 0, stream>>>(xyz, featT, outF, idx0, wp + WP00, b00,
                                            y0us, st0);
    p2_kernel<64, 64><<<2048, 256, 0, stream>>>(y0us, wp + WP01, b01, g00, be00,
                                                st0, n0, y1us, st1, 16384);
    p3_kernel<64, 32><<<2048, 256, 0, stream>>>(y1us, wp + WP02, b02, g01, be01,
                                                st1, n0, maxtmp, st2);
    out_kernel<<<4096, 256, 0, stream>>>(maxtmp, st2, g02, be02, n0, outFeat, 0);

    // ---- scale 1: K=64, 67->64->96->128 ----
    p1_kernel<64><<<2048, 256, 0, stream>>>(xyz, featT, outF, idx1, wp + WP10, b10,
                                            y0us, st3);
    p2_kernel<64, 96><<<2048, 256, 0, stream>>>(y0us, wp + WP11, b11, g10, be10,
                                                st3, n1, y1us, st4, 32768);
    p3_kernel<96, 64><<<2048, 256, 0, stream>>>(y1us, wp + WP12, b12, g11, be11,
                                                st4, n1, maxtmp, st5);
    out_kernel<<<4096, 256, 0, stream>>>(maxtmp, st5, g12, be12, n1, outFeat, 128);
    return;
  }

#define LAUNCH_SCALE0(STG, ST)                                                          \
  do {                                                                                  \
    if (useFT)                                                                          \
      stage_mfma<32, 64, 64, 128, STG, true><<<2048, 256, 0, stream>>>(                 \
          xyz, feat, featT, outF, idx0, wp + WP00, wp + WP01, wp + WP02, b00, b01, b02, \
          ac + 0 * 256, ac + 1 * 256, ST, maxtmp);                                      \
    else                                                                                \
      stage_mfma<32, 64, 64, 128, STG, false><<<2048, 256, 0, stream>>>(                \
          xyz, feat, featT, outF, idx0, wp + WP00, wp + WP01, wp + WP02, b00, b01, b02, \
          ac + 0 * 256, ac + 1 * 256, ST, maxtmp);                                      \
  } while (0)
#define LAUNCH_SCALE1(STG, ST)                                                          \
  do {                                                                                  \
    if (useFT)                                                                          \
      stage_mfma<64, 64, 96, 128, STG, true><<<2048, 256, 0, stream>>>(                 \
          xyz, feat, featT, outF, idx1, wp + WP10, wp + WP11, wp + WP12, b10, b11, b12, \
          ac + 3 * 256, ac + 4 * 256, ST, maxtmp);                                      \
    else                                                                                \
      stage_mfma<64, 64, 96, 128, STG, false><<<2048, 256, 0, stream>>>(                \
          xyz, feat, featT, outF, idx1, wp + WP10, wp + WP11, wp + WP12, b10, b11, b12, \
          ac + 3 * 256, ac + 4 * 256, ST, maxtmp);                                      \
  } while (0)

  LAUNCH_SCALE0(1, st0);
  finalize_kernel<<<1, 128, 0, stream>>>(st0, g00, be00, ac + 0 * 256, n0, 64);
  LAUNCH_SCALE0(2, st1);
  finalize_kernel<<<1, 128, 0, stream>>>(st1, g01, be01, ac + 1 * 256, n0, 64);
  LAUNCH_SCALE0(3, st2);
  out_kernel<<<4096, 256, 0, stream>>>(maxtmp, st2, g02, be02, n0, outFeat, 0);

  LAUNCH_SCALE1(1, st3);
  finalize_kernel<<<1, 128, 0, stream>>>(st3, g10, be10, ac + 3 * 256, n1, 64);
  LAUNCH_SCALE1(2, st4);
  finalize_kernel<<<1, 128, 0, stream>>>(st4, g11, be11, ac + 4 * 256, n1, 96);
  LAUNCH_SCALE1(3, st5);
  out_kernel<<<4096, 256, 0, stream>>>(maxtmp, st5, g12, be12, n1, outFeat, 128);

#undef LAUNCH_SCALE0
#undef LAUNCH_SCALE1
}